// Round 8
// baseline (1817.137 us; speedup 1.0000x reference)
//
#include <hip/hip_runtime.h>
#include <math.h>

#define DI static __device__ __forceinline__

DI float eluf(float x){ return x > 0.f ? x : expm1f(x); }
DI float lreluf(float x){ return x > 0.f ? x : 0.2f*x; }
DI float sigmf(float x){ return 1.f/(1.f+expf(-x)); }

constexpr int N=200, E=3200, HID=64, NH=16, OUTD=128, CAT=2048, SEQD=2240;

// ---- per-graph f32 scratch offsets (in floats) ----
constexpr int OH0   = 0;
constexpr int OWH   = OH0 + N*HID;
constexpr int OASN  = OWH + NH*N*OUTD;
constexpr int OADN  = OASN + NH*N;
constexpr int OH1   = OADN + NH*N;
constexpr int OXW1  = OH1 + N*CAT;
constexpr int OXW2  = OXW1 + 256;
constexpr int OEW1  = OXW2 + 256;
constexpr int OS1   = OEW1 + E;
constexpr int ODEG1 = OS1 + E;
constexpr int OSS1  = ODEG1 + 256;
constexpr int ONS1  = OSS1 + 256;
constexpr int OWH2  = ONS1 + 256;
constexpr int OAS2  = OWH2 + N*OUTD;
constexpr int OAD2  = OAS2 + 256;
constexpr int OEWV  = OAD2 + 256;
constexpr int OH2B  = OEWV + E;
constexpr int OXS2  = OH2B + N*OUTD;
constexpr int OXD2  = OXS2 + 256;
constexpr int OEW2  = OXD2 + 256;
constexpr int OS2   = OEW2 + E;
constexpr int ODEG2 = OS2 + E;
constexpr int OSS2  = ODEG2 + 256;
constexpr int ONS2  = OSS2 + 256;
constexpr int OGATE = ONS2 + 256;
constexpr int PGF   = OGATE + 256;
constexpr int GLOBF = 10624;
constexpr int TOTF  = GLOBF + 2*PGF;

// ---- static device scratch: independent of ws_size ----
__device__ float G_F[TOTF];
__device__ float G_E2PART[(size_t)NH*2*E*OUTD];   // per-head e2 partials (52 MB, no zero needed)
__device__ float G_EDOTH[2*NH*E];                  // eattr@weae per (g,h,e)
__device__ int   G_PIDX[2*N*N];

DI float* gf(int g){ return G_F + GLOBF + (size_t)g*PGF; }
DI float* gwe_ae(){ return G_F; }
DI float* gv_e(){ return G_F + 1024; }
DI float* gy0(){ return G_F + 3072; }
DI float* gy1(){ return G_F + 3584; }
DI float* gxseq(){ return G_F + 4096; }
DI float* gxg(){ return G_F + 8576; }
DI int*   gpidx(int g){ return G_PIDX + g*N*N; }

struct GraphIn {
  const float *feat, *eattr, *adj, *n2n;
  const int   *eidx;
};

struct Params {
  GraphIn g[2];
  const float *W_h, *W_gat, *a_src, *a_dst, *a_e, *We_gat;
  const float *W_out, *ao_src, *ao_dst, *ao_e, *We_out;
  const float *ep1_w, *ep1_b, *ep2_w, *ep2_b;
  const float *g1_w, *g1_b, *g2_w, *g2_b, *g3_w, *g3_b;
  const float *Wih0, *Whh0, *b0, *Wih1, *Whh1, *b1, *fc_w, *fc_b;
  float *out;
};

// ---------------- zero scratch; pairIdx=-1 ----------------
__global__ void k_zero(){
  int idx = blockIdx.x*256 + threadIdx.x;
  if (idx < TOTF) G_F[idx] = 0.f;
  if (idx < 2*N*N) G_PIDX[idx] = -1;
}

// ---------------- precontract We@a_e vectors ----------------
__global__ void k_pre(Params P){
  int idx = blockIdx.x*256 + threadIdx.x;
  if (idx < NH*HID){
    int h = idx/HID, c = idx%HID;
    const float* W = P.We_gat + (size_t)(h*HID + c)*OUTD;
    const float* a = P.a_e + h*OUTD;
    float acc = 0.f;
    for (int o=0;o<OUTD;o++) acc += W[o]*a[o];
    gwe_ae()[idx] = acc;
  } else if (idx < NH*HID + CAT){
    int c = idx - NH*HID;
    const float* W = P.We_out + (size_t)c*OUTD;
    float acc = 0.f;
    for (int o=0;o<OUTD;o++) acc += W[o]*P.ao_e[o];
    gv_e()[c] = acc;
  }
}

// ---- EDOTH[g][h][e] = eattr[e] . weae[h] ----
__global__ void k_edoth(Params P){
  int h = blockIdx.x, g = blockIdx.y;
  const float* weae = gwe_ae() + h*HID;
  for (int e = threadIdx.x; e < E; e += 256){
    const float* row = P.g[g].eattr + (size_t)e*HID;
    float acc = 0.f;
    for (int c=0;c<HID;c++) acc += row[c]*weae[c];
    G_EDOTH[((size_t)g*NH+h)*E + e] = acc;
  }
}

// ---------------- h0 = elu(feat @ W_h) ----------------
__global__ void k_h0(Params P){
  int idx = blockIdx.x*256 + threadIdx.x;
  if (idx >= 2*N*HID) return;
  int g = idx/(N*HID), r = idx%(N*HID), n = r/HID, c = r%HID;
  const float* feat = P.g[g].feat;
  float acc = 0.f;
  for (int k=0;k<HID;k++) acc += feat[n*HID+k]*P.W_h[k*HID+c];
  gf(g)[OH0 + n*HID + c] = eluf(acc);
}

// ---------------- Wh[h] = h0 @ W_gat[h] ----------------
__global__ void k_Wh(Params P){
  int n = blockIdx.x, h = blockIdx.y, g = blockIdx.z, o = threadIdx.x;
  __shared__ float hs[HID];
  float* f = gf(g);
  if (o < HID) hs[o] = f[OH0 + n*HID + o];
  __syncthreads();
  const float* W = P.W_gat + (size_t)h*HID*OUTD + o;
  float acc = 0.f;
  for (int c=0;c<HID;c++) acc += hs[c]*W[(size_t)c*OUTD];
  f[OWH + ((size_t)h*N + n)*OUTD + o] = acc;
}

// ---------------- asn/adn = Wh @ a_src / a_dst ----------------
__global__ void k_asad(Params P){
  int h = blockIdx.x, g = blockIdx.y;
  float* f = gf(g);
  for (int n = threadIdx.x; n < N; n += 256){
    const float* wh = f + OWH + ((size_t)h*N + n)*OUTD;
    float s=0.f, d=0.f;
    for (int o=0;o<OUTD;o++){
      float v = wh[o];
      s += v*P.a_src[h*OUTD+o];
      d += v*P.a_dst[h*OUTD+o];
    }
    f[OASN + h*N + n] = s;
    f[OADN + h*N + n] = d;
  }
}

// ---------------- GAT layer 1: edge term via EDOTH lookup ----------------
__global__ void k_att1(Params P){
  int n = blockIdx.x, h = blockIdx.y, g = blockIdx.z, tid = threadIdx.x;
  __shared__ float z[N];
  __shared__ float red[128];
  float* f = gf(g);
  const float* adj = P.g[g].adj;
  const int* pidx = gpidx(g);
  const float* edoth = G_EDOTH + ((size_t)g*NH + h)*E;
  float asn = f[OASN + h*N + n];
  const float* adn = f + OADN + h*N;
  for (int j = tid; j < N; j += 128){
    float a = adj[n*N + j];
    float zz;
    if (a > 0.f){
      int p = pidx[n*N + j];
      float ee = (p >= 0) ? edoth[p] : 0.f;
      zz = lreluf(asn + adn[j] + ee);
    } else zz = -1e9f;
    z[j] = zz;
  }
  __syncthreads();
  float m = -3e38f;
  for (int j = tid; j < N; j += 128) m = fmaxf(m, z[j]);
  red[tid] = m; __syncthreads();
  for (int s=64;s>0;s>>=1){ if (tid<s) red[tid]=fmaxf(red[tid],red[tid+s]); __syncthreads(); }
  m = red[0]; __syncthreads();
  float ssum = 0.f;
  for (int j = tid; j < N; j += 128){ float e = expf(z[j]-m); z[j]=e; ssum += e; }
  red[tid] = ssum; __syncthreads();
  for (int s=64;s>0;s>>=1){ if (tid<s) red[tid]+=red[tid+s]; __syncthreads(); }
  float inv = 1.f/red[0]; __syncthreads();
  const float* wh = f + OWH + (size_t)h*N*OUTD;
  float acc = 0.f;
  for (int j=0;j<N;j++){
    float w = z[j];
    if (w != 0.f) acc += w * wh[(size_t)j*OUTD + tid];
  }
  f[OH1 + (size_t)n*CAT + h*OUTD + tid] = eluf(acc*inv);
}

// ---- edge dots, head-split, float4 LDS broadcasts ----
constexpr int TE1 = 8;
__global__ void k_edot1(Params P){
  int e0 = blockIdx.x*TE1, h = blockIdx.y, g = blockIdx.z, tid = threadIdx.x; // 128 thr
  __shared__ float es[TE1][HID];
  __shared__ float lred[2][TE1][2];
  const float* ea = P.g[g].eattr + (size_t)e0*HID;
  for (int i = tid; i < TE1*HID; i += 128) ((float*)es)[i] = ea[i];
  __syncthreads();
  const float* W = P.We_gat + (size_t)(h*HID)*OUTD + tid;
  float t[TE1];
  for (int e=0;e<TE1;e++) t[e]=0.f;
  for (int c4=0;c4<HID/4;c4++){
    float4 w;
    w.x = W[(size_t)(4*c4+0)*OUTD];
    w.y = W[(size_t)(4*c4+1)*OUTD];
    w.z = W[(size_t)(4*c4+2)*OUTD];
    w.w = W[(size_t)(4*c4+3)*OUTD];
    for (int e=0;e<TE1;e++){
      float4 ev = ((const float4*)es[e])[c4];
      t[e] += ev.x*w.x + ev.y*w.y + ev.z*w.z + ev.w*w.w;
    }
  }
  float w1 = P.ep1_w[2*CAT + h*OUTD + tid];
  float wv = gv_e()[h*OUTD + tid];
  int lane = tid & 63, wvi = tid >> 6;
  for (int e=0;e<TE1;e++){
    float u = eluf(t[e]);
    float v1 = u*w1, v2 = u*wv;
    for (int off=32;off>0;off>>=1){ v1 += __shfl_down(v1,off); v2 += __shfl_down(v2,off); }
    if (lane==0){ lred[wvi][e][0]=v1; lred[wvi][e][1]=v2; }
  }
  __syncthreads();
  if (tid < TE1*2){
    int e = tid>>1, which = tid&1;
    float s = lred[0][e][which]+lred[1][e][which];
    atomicAdd(&gf(g)[(which? OEWV:OEW1) + e0+e], s);
  }
}

// ---------------- pool1 node dots ----------------
__global__ void k_xw1(Params P){
  int n = blockIdx.x, wch = blockIdx.y, g = blockIdx.z, tid = threadIdx.x;
  __shared__ float sb[256];
  float* f = gf(g);
  const float* x = f + OH1 + (size_t)n*CAT;
  const float* w = P.ep1_w + wch*CAT;
  float acc = 0.f;
  for (int c = tid; c < CAT; c += 256) acc += x[c]*w[c];
  sb[tid] = acc; __syncthreads();
  for (int s=128;s>0;s>>=1){ if (tid<s) sb[tid]+=sb[tid+s]; __syncthreads(); }
  if (tid==0) f[(wch? OXW2:OXW1) + n] = sb[0];
}

// ---------------- pool1 edge scores + segment sums ----------------
__global__ void k_s1(Params P){
  int e = blockIdx.x*256 + threadIdx.x, g = blockIdx.y;
  if (e >= E) return;
  float* f = gf(g);
  const int* ei = P.g[g].eidx;
  int s = ei[e], d = ei[E+e];
  float v = sigmf(f[OXW1+s] + f[OXW2+d] + f[OEW1+e] + P.ep1_b[0]);
  f[OS1+e] = v;
  atomicAdd(&f[OSS1+s], v);
  atomicAdd(&f[ODEG1+s], 1.f);
}

__global__ void k_ns(int odeg, int oss, int ons){
  int g = blockIdx.y, n = threadIdx.x;
  if (n < N){ float* f = gf(g); f[ons+n] = f[oss+n]/(f[odeg+n]+1e-6f); }
}

// ---------------- pairIdx: last edge wins ----------------
__global__ void k_pairs(Params P){
  int e = blockIdx.x*256 + threadIdx.x, g = blockIdx.y;
  if (e >= E) return;
  const int* ei = P.g[g].eidx;
  atomicMax(&gpidx(g)[ei[e]*N + ei[E+e]], e);
}

// ---------------- global attention pool ----------------
__global__ void k_gpool_gate(Params P, int xoff, int D, int scaleoff, const float* w, const float* b){
  int n = blockIdx.x, g = blockIdx.y, tid = threadIdx.x;
  __shared__ float sb[256];
  float* f = gf(g);
  const float* x = f + xoff + (size_t)n*D;
  float acc = 0.f;
  for (int c = tid; c < D; c += 256) acc += x[c]*w[c];
  sb[tid] = acc; __syncthreads();
  for (int s=128;s>0;s>>=1){ if (tid<s) sb[tid]+=sb[tid+s]; __syncthreads(); }
  if (tid==0){
    float sc = scaleoff>=0 ? f[scaleoff+n] : 1.f;
    f[OGATE+n] = sigmf(sb[0]*sc + b[0]);
  }
}

__global__ void k_gpool_out(Params P, int xoff, int D, int scaleoff, int outoff){
  int g = blockIdx.x, tid = threadIdx.x;
  __shared__ float att[N];
  __shared__ float sb[256];
  float* f = gf(g);
  float m = -3e38f;
  for (int n = tid; n < N; n += 256) m = fmaxf(m, f[OGATE+n]);
  sb[tid] = m; __syncthreads();
  for (int s=128;s>0;s>>=1){ if (tid<s) sb[tid]=fmaxf(sb[tid],sb[tid+s]); __syncthreads(); }
  m = sb[0]; __syncthreads();
  float ss = 0.f;
  for (int n = tid; n < N; n += 256){ float e = expf(f[OGATE+n]-m); att[n]=e; ss += e; }
  sb[tid] = ss; __syncthreads();
  for (int s=128;s>0;s>>=1){ if (tid<s) sb[tid]+=sb[tid+s]; __syncthreads(); }
  float inv = 1.f/sb[0]; __syncthreads();
  for (int n = tid; n < N; n += 256){
    float sc = scaleoff>=0 ? f[scaleoff+n] : 1.f;
    att[n] *= inv*sc;
  }
  __syncthreads();
  const float* x = f + xoff;
  for (int c = tid; c < D; c += 256){
    float acc = 0.f;
    for (int n=0;n<N;n++) acc += att[n]*x[(size_t)n*D + c];
    gxseq()[g*SEQD + outoff + c] = acc;
  }
}

// ---------------- Wh2 = (h1cat @ W_out) * ns1 ----------------
__global__ void k_Wh2(Params P){
  int n = blockIdx.x, g = blockIdx.y, tid = threadIdx.x;
  __shared__ float hrow[128];
  float* f = gf(g);
  const float* x = f + OH1 + (size_t)n*CAT;
  float ns = f[ONS1+n];
  float acc = 0.f;
  for (int c0=0;c0<CAT;c0+=128){
    __syncthreads();
    hrow[tid] = x[c0+tid];
    __syncthreads();
    const float* W = P.W_out + (size_t)c0*OUTD + tid;
    for (int cc4=0;cc4<32;cc4++){
      float4 hv = ((const float4*)hrow)[cc4];
      acc += hv.x*W[(size_t)(4*cc4+0)*OUTD]
           + hv.y*W[(size_t)(4*cc4+1)*OUTD]
           + hv.z*W[(size_t)(4*cc4+2)*OUTD]
           + hv.w*W[(size_t)(4*cc4+3)*OUTD];
    }
  }
  f[OWH2 + (size_t)n*OUTD + tid] = acc*ns;
}

__global__ void k_asad2(Params P){
  int g = blockIdx.x;
  float* f = gf(g);
  for (int n = threadIdx.x; n < N; n += 256){
    const float* wh = f + OWH2 + (size_t)n*OUTD;
    float s=0.f, d=0.f;
    for (int o=0;o<OUTD;o++){
      float v = wh[o];
      s += v*P.ao_src[o];
      d += v*P.ao_dst[o];
    }
    f[OAS2+n]=s; f[OAD2+n]=d;
  }
}

// ---------------- GAT layer 2 ----------------
__global__ void k_att2(Params P){
  int n = blockIdx.x, g = blockIdx.y, tid = threadIdx.x;
  __shared__ float z[N];
  __shared__ float red[128];
  float* f = gf(g);
  const float* adj = P.g[g].adj;
  const int* pidx = gpidx(g);
  float asn = f[OAS2+n];
  const float* adn = f + OAD2;
  for (int j = tid; j < N; j += 128){
    float a = adj[n*N + j];
    float zz;
    if (a > 0.f){
      int p = pidx[n*N + j];
      float ee = (p >= 0) ? f[OEWV+p]*f[OS1+p] : 0.f;
      zz = lreluf(asn + adn[j] + ee);
    } else zz = -1e9f;
    z[j] = zz;
  }
  __syncthreads();
  float m = -3e38f;
  for (int j = tid; j < N; j += 128) m = fmaxf(m, z[j]);
  red[tid] = m; __syncthreads();
  for (int s=64;s>0;s>>=1){ if (tid<s) red[tid]=fmaxf(red[tid],red[tid+s]); __syncthreads(); }
  m = red[0]; __syncthreads();
  float ssum = 0.f;
  for (int j = tid; j < N; j += 128){ float e = expf(z[j]-m); z[j]=e; ssum += e; }
  red[tid] = ssum; __syncthreads();
  for (int s=64;s>0;s>>=1){ if (tid<s) red[tid]+=red[tid+s]; __syncthreads(); }
  float inv = 1.f/red[0]; __syncthreads();
  const float* wh = f + OWH2;
  float acc = 0.f;
  for (int j=0;j<N;j++){
    float w = z[j];
    if (w != 0.f) acc += w * wh[(size_t)j*OUTD + tid];
  }
  f[OH2B + (size_t)n*OUTD + tid] = acc*inv;
}

// ---- e2 partial: head-split, plain stores (no atomics), float4 LDS reads ----
constexpr int TE2 = 16;
__global__ void k_e2p(Params P){
  int e0 = blockIdx.x*TE2, h = blockIdx.y, g = blockIdx.z, tid = threadIdx.x; // 128 thr
  __shared__ float es[TE2][HID];
  __shared__ float tcol[TE2][OUTD];
  const float* ea = P.g[g].eattr + (size_t)e0*HID;
  for (int i = tid; i < TE2*HID; i += 128) ((float*)es)[i] = ea[i];
  __syncthreads();
  const float* W1 = P.We_gat + (size_t)(h*HID)*OUTD + tid;
  float t[TE2];
  for (int e=0;e<TE2;e++) t[e]=0.f;
  for (int c4=0;c4<HID/4;c4++){
    float4 w;
    w.x = W1[(size_t)(4*c4+0)*OUTD];
    w.y = W1[(size_t)(4*c4+1)*OUTD];
    w.z = W1[(size_t)(4*c4+2)*OUTD];
    w.w = W1[(size_t)(4*c4+3)*OUTD];
    for (int e=0;e<TE2;e++){
      float4 ev = ((const float4*)es[e])[c4];
      t[e] += ev.x*w.x + ev.y*w.y + ev.z*w.z + ev.w*w.w;
    }
  }
  for (int e=0;e<TE2;e++) tcol[e][tid] = eluf(t[e]);
  __syncthreads();
  float acc[TE2];
  for (int e=0;e<TE2;e++) acc[e]=0.f;
  const float* W2 = P.We_out + (size_t)(h*OUTD)*OUTD + tid;
  for (int o4=0;o4<OUTD/4;o4++){
    float4 w;
    w.x = W2[(size_t)(4*o4+0)*OUTD];
    w.y = W2[(size_t)(4*o4+1)*OUTD];
    w.z = W2[(size_t)(4*o4+2)*OUTD];
    w.w = W2[(size_t)(4*o4+3)*OUTD];
    for (int e=0;e<TE2;e++){
      float4 tv = ((const float4*)tcol[e])[o4];
      acc[e] += tv.x*w.x + tv.y*w.y + tv.z*w.z + tv.w*w.w;
    }
  }
  float* dst = G_E2PART + (((size_t)h*2 + g)*E + e0)*OUTD + tid;
  for (int e=0;e<TE2;e++) dst[(size_t)e*OUTD] = acc[e];
}

// ---- finish: sum 16 head-partials, elu, dot ep2_w ----
__global__ void k_ew2fin(Params P){
  int e0 = blockIdx.x*TE2, g = blockIdx.y, tid = threadIdx.x;  // 128 thr
  __shared__ float lred[2][TE2];
  float* f = gf(g);
  float w2 = P.ep2_w[2*OUTD + tid];
  int lane = tid & 63, wvi = tid >> 6;
  for (int e=0;e<TE2;e++){
    const float* src = G_E2PART + ((size_t)g*E + e0 + e)*OUTD + tid;
    float a = 0.f;
    for (int h=0;h<NH;h++) a += src[(size_t)h*2*E*OUTD];
    float v = eluf(f[OS1+e0+e]*a) * w2;
    for (int off=32;off>0;off>>=1) v += __shfl_down(v,off);
    if (lane==0) lred[wvi][e]=v;
  }
  __syncthreads();
  if (tid < TE2) f[OEW2+e0+tid] = lred[0][tid]+lred[1][tid];
}

// ---------------- pool2 node dots ----------------
__global__ void k_xsd2(Params P){
  int g = blockIdx.x;
  float* f = gf(g);
  for (int n = threadIdx.x; n < N; n += 256){
    const float* x = f + OH2B + (size_t)n*OUTD;
    float s=0.f, d=0.f;
    for (int k=0;k<OUTD;k++){
      float v = x[k];
      s += v*P.ep2_w[k];
      d += v*P.ep2_w[OUTD+k];
    }
    f[OXS2+n]=s; f[OXD2+n]=d;
  }
}

__global__ void k_s2(Params P){
  int e = blockIdx.x*256 + threadIdx.x, g = blockIdx.y;
  if (e >= E) return;
  float* f = gf(g);
  const int* ei = P.g[g].eidx;
  int s = ei[e], d = ei[E+e];
  float v = sigmf(f[OXS2+s] + f[OXD2+d] + f[OEW2+e] + P.ep2_b[0]);
  f[OS2+e] = v;
  atomicAdd(&f[OSS2+s], v);
  atomicAdd(&f[ODEG2+s], 1.f);
}

// ---- LSTM input projection ----
__global__ void k_lstm_xg(Params P, int layer){
  int gid = blockIdx.x*4 + (threadIdx.x>>6);
  int lane = threadIdx.x & 63;
  int t = gid >> 10;
  int rem = gid & 1023;
  int d = rem >> 9;
  int gate = rem & 511;
  const float* Wih = layer ? P.Wih1 : P.Wih0;
  const float* bb  = layer ? P.b1   : P.b0;
  const float* xin = layer ? gy0()  : gxseq();
  int Din = layer ? 256 : SEQD;
  const float* x = xin + t*Din;
  const float* Wr = Wih + ((size_t)d*512 + gate)*Din;
  float acc = 0.f;
  for (int k=lane; k<Din; k+=64) acc += x[k]*Wr[k];
  for (int off=32; off>0; off>>=1) acc += __shfl_down(acc, off);
  if (lane==0) gxg()[(t*2 + d)*512 + gate] = acc + bb[d*512 + gate];
}

// ---- LSTM recurrence only ----
__global__ void k_lstm_rec(Params P, int layer){
  int d = blockIdx.x, tid = threadIdx.x;
  const float* Whh = layer ? P.Whh1 : P.Whh0;
  float* yout = layer ? gy1() : gy0();
  __shared__ float h[128], c[128], gbuf[512];
  if (tid < 128){ h[tid]=0.f; c[tid]=0.f; }
  __syncthreads();
  for (int s=0;s<2;s++){
    int t = (d==0) ? s : 1-s;
    float acc = gxg()[(t*2 + d)*512 + tid];
    const float* Ur = Whh + ((size_t)d*512 + tid)*128;
    for (int k=0;k<128;k++) acc += h[k]*Ur[k];
    gbuf[tid] = acc;
    __syncthreads();
    if (tid < 128){
      float ii = sigmf(gbuf[tid]);
      float ff = sigmf(gbuf[128+tid]);
      float gg = tanhf(gbuf[256+tid]);
      float oo = sigmf(gbuf[384+tid]);
      float cn = ff*c[tid] + ii*gg;
      c[tid] = cn;
      float hn = oo*tanhf(cn);
      h[tid] = hn;
      yout[t*256 + d*128 + tid] = hn;
    }
    __syncthreads();
  }
}

// ---------------- final FC + softmax ----------------
__global__ void k_final(Params P){
  int tid = threadIdx.x;
  __shared__ float sb[256], sb2[256];
  const float* x = gy1() + 256;
  sb[tid]  = x[tid]*P.fc_w[tid*2+0];
  sb2[tid] = x[tid]*P.fc_w[tid*2+1];
  __syncthreads();
  for (int s=128;s>0;s>>=1){ if (tid<s){ sb[tid]+=sb[tid+s]; sb2[tid]+=sb2[tid+s]; } __syncthreads(); }
  if (tid==0){
    float l0 = sb[0] + P.fc_b[0];
    float l1 = sb2[0] + P.fc_b[1];
    float m = fmaxf(l0,l1);
    float e0 = expf(l0-m), e1 = expf(l1-m), inv = 1.f/(e0+e1);
    P.out[0] = e0*inv;
    P.out[1] = e1*inv;
  }
}

extern "C" void kernel_launch(void* const* d_in, const int* in_sizes, int n_in,
                              void* d_out, int out_size, void* d_ws, size_t ws_size,
                              hipStream_t stream){
  Params P;
  for (int g=0; g<2; ++g){
    int b = g*5;
    P.g[g].feat  = (const float*)d_in[b+0];
    P.g[g].eidx  = (const int*)d_in[b+1];
    P.g[g].eattr = (const float*)d_in[b+2];
    P.g[g].adj   = (const float*)d_in[b+3];
    P.g[g].n2n   = (const float*)d_in[b+4];
  }
  P.W_h   = (const float*)d_in[10];
  P.W_gat = (const float*)d_in[11];
  P.a_src = (const float*)d_in[12];
  P.a_dst = (const float*)d_in[13];
  P.a_e   = (const float*)d_in[14];
  P.We_gat= (const float*)d_in[15];
  P.W_out = (const float*)d_in[16];
  P.ao_src= (const float*)d_in[17];
  P.ao_dst= (const float*)d_in[18];
  P.ao_e  = (const float*)d_in[19];
  P.We_out= (const float*)d_in[20];
  P.ep1_w = (const float*)d_in[21];
  P.ep1_b = (const float*)d_in[22];
  P.ep2_w = (const float*)d_in[23];
  P.ep2_b = (const float*)d_in[24];
  P.g1_w  = (const float*)d_in[25];
  P.g1_b  = (const float*)d_in[26];
  P.g2_w  = (const float*)d_in[27];
  P.g2_b  = (const float*)d_in[28];
  P.g3_w  = (const float*)d_in[29];
  P.g3_b  = (const float*)d_in[30];
  P.Wih0  = (const float*)d_in[31];
  P.Whh0  = (const float*)d_in[32];
  P.b0    = (const float*)d_in[33];
  P.Wih1  = (const float*)d_in[34];
  P.Whh1  = (const float*)d_in[35];
  P.b1    = (const float*)d_in[36];
  P.fc_w  = (const float*)d_in[37];
  P.fc_b  = (const float*)d_in[38];
  P.out   = (float*)d_out;

  // ---- graph stages ----
  k_zero <<<dim3((TOTF+255)/256 + 1), 256, 0, stream>>>();
  k_pre  <<<dim3((NH*HID+CAT+255)/256), 256, 0, stream>>>(P);
  k_pairs<<<dim3((E+255)/256,2), 256, 0, stream>>>(P);
  k_edoth<<<dim3(NH,2),   256, 0, stream>>>(P);
  k_h0   <<<dim3((2*N*HID+255)/256), 256, 0, stream>>>(P);
  k_gpool_gate<<<dim3(N,2), 256, 0, stream>>>(P, OH0, HID, -1, P.g1_w, P.g1_b);
  k_gpool_out <<<dim3(2),   256, 0, stream>>>(P, OH0, HID, -1, 0);
  k_Wh   <<<dim3(N,NH,2), 128, 0, stream>>>(P);
  k_asad <<<dim3(NH,2),   256, 0, stream>>>(P);
  k_att1 <<<dim3(N,NH,2), 128, 0, stream>>>(P);
  k_edot1<<<dim3(E/TE1,NH,2),128, 0, stream>>>(P);
  k_xw1  <<<dim3(N,2,2),  256, 0, stream>>>(P);
  k_s1   <<<dim3((E+255)/256,2), 256, 0, stream>>>(P);
  k_ns   <<<dim3(1,2),    256, 0, stream>>>(ODEG1, OSS1, ONS1);
  k_gpool_gate<<<dim3(N,2), 256, 0, stream>>>(P, OH1, CAT, ONS1, P.g2_w, P.g2_b);
  k_gpool_out <<<dim3(2),   256, 0, stream>>>(P, OH1, CAT, ONS1, HID);
  k_Wh2  <<<dim3(N,2),    128, 0, stream>>>(P);
  k_asad2<<<dim3(2),      256, 0, stream>>>(P);
  k_att2 <<<dim3(N,2),    128, 0, stream>>>(P);
  k_e2p  <<<dim3(E/TE2,NH,2),128, 0, stream>>>(P);
  k_ew2fin<<<dim3(E/TE2,2),128, 0, stream>>>(P);
  k_xsd2 <<<dim3(2),      256, 0, stream>>>(P);
  k_s2   <<<dim3((E+255)/256,2), 256, 0, stream>>>(P);
  k_ns   <<<dim3(1,2),    256, 0, stream>>>(ODEG2, OSS2, ONS2);
  k_gpool_gate<<<dim3(N,2), 256, 0, stream>>>(P, OH2B, OUTD, ONS2, P.g3_w, P.g3_b);
  k_gpool_out <<<dim3(2),   256, 0, stream>>>(P, OH2B, OUTD, ONS2, HID+CAT);

  // ---- LSTM stack + classifier ----
  k_lstm_xg <<<dim3(512), 256, 0, stream>>>(P, 0);
  k_lstm_rec<<<dim3(2),   512, 0, stream>>>(P, 0);
  k_lstm_xg <<<dim3(512), 256, 0, stream>>>(P, 1);
  k_lstm_rec<<<dim3(2),   512, 0, stream>>>(P, 1);
  k_final<<<dim3(1), 256, 0, stream>>>(P);
}

// Round 9
// 706.274 us; speedup vs baseline: 2.5729x; 2.5729x over previous
//
#include <hip/hip_runtime.h>
#include <math.h>

#define DI static __device__ __forceinline__

DI float eluf(float x){ return x > 0.f ? x : expm1f(x); }
DI float lreluf(float x){ return x > 0.f ? x : 0.2f*x; }
DI float sigmf(float x){ return 1.f/(1.f+expf(-x)); }

constexpr int N=200, E=3200, HID=64, NH=16, OUTD=128, CAT=2048, SEQD=2240;

// ---- per-graph f32 scratch offsets (in floats) ----
constexpr int OH0   = 0;
constexpr int OWH   = OH0 + N*HID;
constexpr int OASN  = OWH + NH*N*OUTD;
constexpr int OADN  = OASN + NH*N;
constexpr int OH1   = OADN + NH*N;
constexpr int OXW1  = OH1 + N*CAT;
constexpr int OXW2  = OXW1 + 256;
constexpr int OEW1  = OXW2 + 256;
constexpr int OS1   = OEW1 + E;
constexpr int ODEG1 = OS1 + E;
constexpr int OSS1  = ODEG1 + 256;
constexpr int ONS1  = OSS1 + 256;
constexpr int OWH2  = ONS1 + 256;
constexpr int OAS2  = OWH2 + N*OUTD;
constexpr int OAD2  = OAS2 + 256;
constexpr int OEWV  = OAD2 + 256;
constexpr int OH2B  = OEWV + E;
constexpr int OXS2  = OH2B + N*OUTD;
constexpr int OXD2  = OXS2 + 256;
constexpr int OEW2  = OXD2 + 256;
constexpr int OS2   = OEW2 + E;
constexpr int ODEG2 = OS2 + E;
constexpr int OSS2  = ODEG2 + 256;
constexpr int ONS2  = OSS2 + 256;
constexpr int OGATE = ONS2 + 256;
constexpr int PGF   = OGATE + 256;
constexpr int GLOBF = 10624;
constexpr int TOTF  = GLOBF + 2*PGF;

// ---- static device scratch: independent of ws_size ----
__device__ float G_F[TOTF];
__device__ float G_E2PART[(size_t)NH*2*E*OUTD];   // per-head e2 partials (52 MB, no zero needed)
__device__ float G_EDOTH[2*NH*E];                  // eattr@weae per (g,h,e)
__device__ int   G_PIDX[2*N*N];

DI float* gf(int g){ return G_F + GLOBF + (size_t)g*PGF; }
DI float* gwe_ae(){ return G_F; }
DI float* gv_e(){ return G_F + 1024; }
DI float* gy0(){ return G_F + 3072; }
DI float* gy1(){ return G_F + 3584; }
DI float* gxseq(){ return G_F + 4096; }
DI float* gxg(){ return G_F + 8576; }
DI int*   gpidx(int g){ return G_PIDX + g*N*N; }

struct GraphIn {
  const float *feat, *eattr, *adj, *n2n;
  const int   *eidx;
};

struct Params {
  GraphIn g[2];
  const float *W_h, *W_gat, *a_src, *a_dst, *a_e, *We_gat;
  const float *W_out, *ao_src, *ao_dst, *ao_e, *We_out;
  const float *ep1_w, *ep1_b, *ep2_w, *ep2_b;
  const float *g1_w, *g1_b, *g2_w, *g2_b, *g3_w, *g3_b;
  const float *Wih0, *Whh0, *b0, *Wih1, *Whh1, *b1, *fc_w, *fc_b;
  float *out;
};

// ---------------- zero scratch; pairIdx=-1 ----------------
__global__ void k_zero(){
  int idx = blockIdx.x*256 + threadIdx.x;
  if (idx < TOTF) G_F[idx] = 0.f;
  if (idx < 2*N*N) G_PIDX[idx] = -1;
}

// ---------------- precontract We@a_e vectors ----------------
__global__ void k_pre(Params P){
  int idx = blockIdx.x*256 + threadIdx.x;
  if (idx < NH*HID){
    int h = idx/HID, c = idx%HID;
    const float* W = P.We_gat + (size_t)(h*HID + c)*OUTD;
    const float* a = P.a_e + h*OUTD;
    float acc = 0.f;
    for (int o=0;o<OUTD;o++) acc += W[o]*a[o];
    gwe_ae()[idx] = acc;
  } else if (idx < NH*HID + CAT){
    int c = idx - NH*HID;
    const float* W = P.We_out + (size_t)c*OUTD;
    float acc = 0.f;
    for (int o=0;o<OUTD;o++) acc += W[o]*P.ao_e[o];
    gv_e()[c] = acc;
  }
}

// ---- EDOTH[g][h][e] = eattr[e] . weae[h] ----
__global__ void k_edoth(Params P){
  int h = blockIdx.x, g = blockIdx.y;
  const float* weae = gwe_ae() + h*HID;
  for (int e = threadIdx.x; e < E; e += 256){
    const float* row = P.g[g].eattr + (size_t)e*HID;
    float acc = 0.f;
    for (int c=0;c<HID;c++) acc += row[c]*weae[c];
    G_EDOTH[((size_t)g*NH+h)*E + e] = acc;
  }
}

// ---------------- h0 = elu(feat @ W_h) ----------------
__global__ void k_h0(Params P){
  int idx = blockIdx.x*256 + threadIdx.x;
  if (idx >= 2*N*HID) return;
  int g = idx/(N*HID), r = idx%(N*HID), n = r/HID, c = r%HID;
  const float* feat = P.g[g].feat;
  float acc = 0.f;
  for (int k=0;k<HID;k++) acc += feat[n*HID+k]*P.W_h[k*HID+c];
  gf(g)[OH0 + n*HID + c] = eluf(acc);
}

// ---------------- Wh[h] = h0 @ W_gat[h] ----------------
__global__ void k_Wh(Params P){
  int n = blockIdx.x, h = blockIdx.y, g = blockIdx.z, o = threadIdx.x;
  __shared__ float hs[HID];
  float* f = gf(g);
  if (o < HID) hs[o] = f[OH0 + n*HID + o];
  __syncthreads();
  const float* W = P.W_gat + (size_t)h*HID*OUTD + o;
  float acc = 0.f;
  for (int c=0;c<HID;c++) acc += hs[c]*W[(size_t)c*OUTD];
  f[OWH + ((size_t)h*N + n)*OUTD + o] = acc;
}

// ---------------- asn/adn = Wh @ a_src / a_dst ----------------
__global__ void k_asad(Params P){
  int h = blockIdx.x, g = blockIdx.y;
  float* f = gf(g);
  for (int n = threadIdx.x; n < N; n += 256){
    const float* wh = f + OWH + ((size_t)h*N + n)*OUTD;
    float s=0.f, d=0.f;
    for (int o=0;o<OUTD;o++){
      float v = wh[o];
      s += v*P.a_src[h*OUTD+o];
      d += v*P.a_dst[h*OUTD+o];
    }
    f[OASN + h*N + n] = s;
    f[OADN + h*N + n] = d;
  }
}

// ---------------- GAT layer 1: edge term via EDOTH lookup ----------------
__global__ void k_att1(Params P){
  int n = blockIdx.x, h = blockIdx.y, g = blockIdx.z, tid = threadIdx.x;
  __shared__ float z[N];
  __shared__ float red[128];
  float* f = gf(g);
  const float* adj = P.g[g].adj;
  const int* pidx = gpidx(g);
  const float* edoth = G_EDOTH + ((size_t)g*NH + h)*E;
  float asn = f[OASN + h*N + n];
  const float* adn = f + OADN + h*N;
  for (int j = tid; j < N; j += 128){
    float a = adj[n*N + j];
    float zz;
    if (a > 0.f){
      int p = pidx[n*N + j];
      float ee = (p >= 0) ? edoth[p] : 0.f;
      zz = lreluf(asn + adn[j] + ee);
    } else zz = -1e9f;
    z[j] = zz;
  }
  __syncthreads();
  float m = -3e38f;
  for (int j = tid; j < N; j += 128) m = fmaxf(m, z[j]);
  red[tid] = m; __syncthreads();
  for (int s=64;s>0;s>>=1){ if (tid<s) red[tid]=fmaxf(red[tid],red[tid+s]); __syncthreads(); }
  m = red[0]; __syncthreads();
  float ssum = 0.f;
  for (int j = tid; j < N; j += 128){ float e = expf(z[j]-m); z[j]=e; ssum += e; }
  red[tid] = ssum; __syncthreads();
  for (int s=64;s>0;s>>=1){ if (tid<s) red[tid]+=red[tid+s]; __syncthreads(); }
  float inv = 1.f/red[0]; __syncthreads();
  const float* wh = f + OWH + (size_t)h*N*OUTD;
  float acc = 0.f;
  for (int j=0;j<N;j++){
    float w = z[j];
    if (w != 0.f) acc += w * wh[(size_t)j*OUTD + tid];
  }
  f[OH1 + (size_t)n*CAT + h*OUTD + tid] = eluf(acc*inv);
}

// ---- edge dots, head-split, scalar broadcast inner loop (no spill) ----
constexpr int TE1 = 8;
__global__ void k_edot1(Params P){
  int e0 = blockIdx.x*TE1, h = blockIdx.y, g = blockIdx.z, tid = threadIdx.x; // 128 thr
  __shared__ float es[TE1][HID];
  __shared__ float lred[2][TE1][2];
  const float* ea = P.g[g].eattr + (size_t)e0*HID;
  for (int i = tid; i < TE1*HID; i += 128) ((float*)es)[i] = ea[i];
  __syncthreads();
  const float* W = P.We_gat + (size_t)(h*HID)*OUTD + tid;
  float t[TE1];
  for (int e=0;e<TE1;e++) t[e]=0.f;
  for (int c=0;c<HID;c++){
    float w = W[(size_t)c*OUTD];
    for (int e=0;e<TE1;e++) t[e] += es[e][c]*w;
  }
  float w1 = P.ep1_w[2*CAT + h*OUTD + tid];
  float wv = gv_e()[h*OUTD + tid];
  int lane = tid & 63, wvi = tid >> 6;
  for (int e=0;e<TE1;e++){
    float u = eluf(t[e]);
    float v1 = u*w1, v2 = u*wv;
    for (int off=32;off>0;off>>=1){ v1 += __shfl_down(v1,off); v2 += __shfl_down(v2,off); }
    if (lane==0){ lred[wvi][e][0]=v1; lred[wvi][e][1]=v2; }
  }
  __syncthreads();
  if (tid < TE1*2){
    int e = tid>>1, which = tid&1;
    float s = lred[0][e][which]+lred[1][e][which];
    atomicAdd(&gf(g)[(which? OEWV:OEW1) + e0+e], s);
  }
}

// ---------------- pool1 node dots ----------------
__global__ void k_xw1(Params P){
  int n = blockIdx.x, wch = blockIdx.y, g = blockIdx.z, tid = threadIdx.x;
  __shared__ float sb[256];
  float* f = gf(g);
  const float* x = f + OH1 + (size_t)n*CAT;
  const float* w = P.ep1_w + wch*CAT;
  float acc = 0.f;
  for (int c = tid; c < CAT; c += 256) acc += x[c]*w[c];
  sb[tid] = acc; __syncthreads();
  for (int s=128;s>0;s>>=1){ if (tid<s) sb[tid]+=sb[tid+s]; __syncthreads(); }
  if (tid==0) f[(wch? OXW2:OXW1) + n] = sb[0];
}

// ---------------- pool1 edge scores + segment sums ----------------
__global__ void k_s1(Params P){
  int e = blockIdx.x*256 + threadIdx.x, g = blockIdx.y;
  if (e >= E) return;
  float* f = gf(g);
  const int* ei = P.g[g].eidx;
  int s = ei[e], d = ei[E+e];
  float v = sigmf(f[OXW1+s] + f[OXW2+d] + f[OEW1+e] + P.ep1_b[0]);
  f[OS1+e] = v;
  atomicAdd(&f[OSS1+s], v);
  atomicAdd(&f[ODEG1+s], 1.f);
}

__global__ void k_ns(int odeg, int oss, int ons){
  int g = blockIdx.y, n = threadIdx.x;
  if (n < N){ float* f = gf(g); f[ons+n] = f[oss+n]/(f[odeg+n]+1e-6f); }
}

// ---------------- pairIdx: last edge wins ----------------
__global__ void k_pairs(Params P){
  int e = blockIdx.x*256 + threadIdx.x, g = blockIdx.y;
  if (e >= E) return;
  const int* ei = P.g[g].eidx;
  atomicMax(&gpidx(g)[ei[e]*N + ei[E+e]], e);
}

// ---------------- global attention pool ----------------
__global__ void k_gpool_gate(Params P, int xoff, int D, int scaleoff, const float* w, const float* b){
  int n = blockIdx.x, g = blockIdx.y, tid = threadIdx.x;
  __shared__ float sb[256];
  float* f = gf(g);
  const float* x = f + xoff + (size_t)n*D;
  float acc = 0.f;
  for (int c = tid; c < D; c += 256) acc += x[c]*w[c];
  sb[tid] = acc; __syncthreads();
  for (int s=128;s>0;s>>=1){ if (tid<s) sb[tid]+=sb[tid+s]; __syncthreads(); }
  if (tid==0){
    float sc = scaleoff>=0 ? f[scaleoff+n] : 1.f;
    f[OGATE+n] = sigmf(sb[0]*sc + b[0]);
  }
}

__global__ void k_gpool_out(Params P, int xoff, int D, int scaleoff, int outoff){
  int g = blockIdx.x, tid = threadIdx.x;
  __shared__ float att[N];
  __shared__ float sb[256];
  float* f = gf(g);
  float m = -3e38f;
  for (int n = tid; n < N; n += 256) m = fmaxf(m, f[OGATE+n]);
  sb[tid] = m; __syncthreads();
  for (int s=128;s>0;s>>=1){ if (tid<s) sb[tid]=fmaxf(sb[tid],sb[tid+s]); __syncthreads(); }
  m = sb[0]; __syncthreads();
  float ss = 0.f;
  for (int n = tid; n < N; n += 256){ float e = expf(f[OGATE+n]-m); att[n]=e; ss += e; }
  sb[tid] = ss; __syncthreads();
  for (int s=128;s>0;s>>=1){ if (tid<s) sb[tid]+=sb[tid+s]; __syncthreads(); }
  float inv = 1.f/sb[0]; __syncthreads();
  for (int n = tid; n < N; n += 256){
    float sc = scaleoff>=0 ? f[scaleoff+n] : 1.f;
    att[n] *= inv*sc;
  }
  __syncthreads();
  const float* x = f + xoff;
  for (int c = tid; c < D; c += 256){
    float acc = 0.f;
    for (int n=0;n<N;n++) acc += att[n]*x[(size_t)n*D + c];
    gxseq()[g*SEQD + outoff + c] = acc;
  }
}

// ---------------- Wh2 = (h1cat @ W_out) * ns1 ----------------
__global__ void k_Wh2(Params P){
  int n = blockIdx.x, g = blockIdx.y, tid = threadIdx.x;
  __shared__ float hrow[128];
  float* f = gf(g);
  const float* x = f + OH1 + (size_t)n*CAT;
  float ns = f[ONS1+n];
  float acc = 0.f;
  for (int c0=0;c0<CAT;c0+=128){
    __syncthreads();
    hrow[tid] = x[c0+tid];
    __syncthreads();
    const float* W = P.W_out + (size_t)c0*OUTD + tid;
    for (int cc=0;cc<128;cc++) acc += hrow[cc]*W[(size_t)cc*OUTD];
  }
  f[OWH2 + (size_t)n*OUTD + tid] = acc*ns;
}

__global__ void k_asad2(Params P){
  int g = blockIdx.x;
  float* f = gf(g);
  for (int n = threadIdx.x; n < N; n += 256){
    const float* wh = f + OWH2 + (size_t)n*OUTD;
    float s=0.f, d=0.f;
    for (int o=0;o<OUTD;o++){
      float v = wh[o];
      s += v*P.ao_src[o];
      d += v*P.ao_dst[o];
    }
    f[OAS2+n]=s; f[OAD2+n]=d;
  }
}

// ---------------- GAT layer 2 ----------------
__global__ void k_att2(Params P){
  int n = blockIdx.x, g = blockIdx.y, tid = threadIdx.x;
  __shared__ float z[N];
  __shared__ float red[128];
  float* f = gf(g);
  const float* adj = P.g[g].adj;
  const int* pidx = gpidx(g);
  float asn = f[OAS2+n];
  const float* adn = f + OAD2;
  for (int j = tid; j < N; j += 128){
    float a = adj[n*N + j];
    float zz;
    if (a > 0.f){
      int p = pidx[n*N + j];
      float ee = (p >= 0) ? f[OEWV+p]*f[OS1+p] : 0.f;
      zz = lreluf(asn + adn[j] + ee);
    } else zz = -1e9f;
    z[j] = zz;
  }
  __syncthreads();
  float m = -3e38f;
  for (int j = tid; j < N; j += 128) m = fmaxf(m, z[j]);
  red[tid] = m; __syncthreads();
  for (int s=64;s>0;s>>=1){ if (tid<s) red[tid]=fmaxf(red[tid],red[tid+s]); __syncthreads(); }
  m = red[0]; __syncthreads();
  float ssum = 0.f;
  for (int j = tid; j < N; j += 128){ float e = expf(z[j]-m); z[j]=e; ssum += e; }
  red[tid] = ssum; __syncthreads();
  for (int s=64;s>0;s>>=1){ if (tid<s) red[tid]+=red[tid+s]; __syncthreads(); }
  float inv = 1.f/red[0]; __syncthreads();
  const float* wh = f + OWH2;
  float acc = 0.f;
  for (int j=0;j<N;j++){
    float w = z[j];
    if (w != 0.f) acc += w * wh[(size_t)j*OUTD + tid];
  }
  f[OH2B + (size_t)n*OUTD + tid] = acc*inv;
}

// ---- e2 partial: head-split, plain stores, scalar broadcast loops ----
constexpr int TE2 = 16;
__global__ void k_e2p(Params P){
  int e0 = blockIdx.x*TE2, h = blockIdx.y, g = blockIdx.z, tid = threadIdx.x; // 128 thr
  __shared__ float es[TE2][HID];
  __shared__ float tcol[TE2][OUTD];
  const float* ea = P.g[g].eattr + (size_t)e0*HID;
  for (int i = tid; i < TE2*HID; i += 128) ((float*)es)[i] = ea[i];
  __syncthreads();
  const float* W1 = P.We_gat + (size_t)(h*HID)*OUTD + tid;
  float t[TE2];
  for (int e=0;e<TE2;e++) t[e]=0.f;
  for (int c=0;c<HID;c++){
    float w = W1[(size_t)c*OUTD];
    for (int e=0;e<TE2;e++) t[e] += es[e][c]*w;
  }
  for (int e=0;e<TE2;e++) tcol[e][tid] = eluf(t[e]);
  __syncthreads();
  float acc[TE2];
  for (int e=0;e<TE2;e++) acc[e]=0.f;
  const float* W2 = P.We_out + (size_t)(h*OUTD)*OUTD + tid;
  for (int o=0;o<OUTD;o++){
    float w = W2[(size_t)o*OUTD];
    for (int e=0;e<TE2;e++) acc[e] += tcol[e][o]*w;
  }
  float* dst = G_E2PART + (((size_t)h*2 + g)*E + e0)*OUTD + tid;
  for (int e=0;e<TE2;e++) dst[(size_t)e*OUTD] = acc[e];
}

// ---- finish: sum 16 head-partials, elu, dot ep2_w ----
__global__ void k_ew2fin(Params P){
  int e0 = blockIdx.x*TE2, g = blockIdx.y, tid = threadIdx.x;  // 128 thr
  __shared__ float lred[2][TE2];
  float* f = gf(g);
  float w2 = P.ep2_w[2*OUTD + tid];
  int lane = tid & 63, wvi = tid >> 6;
  for (int e=0;e<TE2;e++){
    const float* src = G_E2PART + ((size_t)g*E + e0 + e)*OUTD + tid;
    float a = 0.f;
    for (int h=0;h<NH;h++) a += src[(size_t)h*2*E*OUTD];
    float v = eluf(f[OS1+e0+e]*a) * w2;
    for (int off=32;off>0;off>>=1) v += __shfl_down(v,off);
    if (lane==0) lred[wvi][e]=v;
  }
  __syncthreads();
  if (tid < TE2) f[OEW2+e0+tid] = lred[0][tid]+lred[1][tid];
}

// ---------------- pool2 node dots ----------------
__global__ void k_xsd2(Params P){
  int g = blockIdx.x;
  float* f = gf(g);
  for (int n = threadIdx.x; n < N; n += 256){
    const float* x = f + OH2B + (size_t)n*OUTD;
    float s=0.f, d=0.f;
    for (int k=0;k<OUTD;k++){
      float v = x[k];
      s += v*P.ep2_w[k];
      d += v*P.ep2_w[OUTD+k];
    }
    f[OXS2+n]=s; f[OXD2+n]=d;
  }
}

__global__ void k_s2(Params P){
  int e = blockIdx.x*256 + threadIdx.x, g = blockIdx.y;
  if (e >= E) return;
  float* f = gf(g);
  const int* ei = P.g[g].eidx;
  int s = ei[e], d = ei[E+e];
  float v = sigmf(f[OXS2+s] + f[OXD2+d] + f[OEW2+e] + P.ep2_b[0]);
  f[OS2+e] = v;
  atomicAdd(&f[OSS2+s], v);
  atomicAdd(&f[ODEG2+s], 1.f);
}

// ---- LSTM input projection ----
__global__ void k_lstm_xg(Params P, int layer){
  int gid = blockIdx.x*4 + (threadIdx.x>>6);
  int lane = threadIdx.x & 63;
  int t = gid >> 10;
  int rem = gid & 1023;
  int d = rem >> 9;
  int gate = rem & 511;
  const float* Wih = layer ? P.Wih1 : P.Wih0;
  const float* bb  = layer ? P.b1   : P.b0;
  const float* xin = layer ? gy0()  : gxseq();
  int Din = layer ? 256 : SEQD;
  const float* x = xin + t*Din;
  const float* Wr = Wih + ((size_t)d*512 + gate)*Din;
  float acc = 0.f;
  for (int k=lane; k<Din; k+=64) acc += x[k]*Wr[k];
  for (int off=32; off>0; off>>=1) acc += __shfl_down(acc, off);
  if (lane==0) gxg()[(t*2 + d)*512 + gate] = acc + bb[d*512 + gate];
}

// ---- LSTM recurrence only ----
__global__ void k_lstm_rec(Params P, int layer){
  int d = blockIdx.x, tid = threadIdx.x;
  const float* Whh = layer ? P.Whh1 : P.Whh0;
  float* yout = layer ? gy1() : gy0();
  __shared__ float h[128], c[128], gbuf[512];
  if (tid < 128){ h[tid]=0.f; c[tid]=0.f; }
  __syncthreads();
  for (int s=0;s<2;s++){
    int t = (d==0) ? s : 1-s;
    float acc = gxg()[(t*2 + d)*512 + tid];
    const float* Ur = Whh + ((size_t)d*512 + tid)*128;
    for (int k=0;k<128;k++) acc += h[k]*Ur[k];
    gbuf[tid] = acc;
    __syncthreads();
    if (tid < 128){
      float ii = sigmf(gbuf[tid]);
      float ff = sigmf(gbuf[128+tid]);
      float gg = tanhf(gbuf[256+tid]);
      float oo = sigmf(gbuf[384+tid]);
      float cn = ff*c[tid] + ii*gg;
      c[tid] = cn;
      float hn = oo*tanhf(cn);
      h[tid] = hn;
      yout[t*256 + d*128 + tid] = hn;
    }
    __syncthreads();
  }
}

// ---------------- final FC + softmax ----------------
__global__ void k_final(Params P){
  int tid = threadIdx.x;
  __shared__ float sb[256], sb2[256];
  const float* x = gy1() + 256;
  sb[tid]  = x[tid]*P.fc_w[tid*2+0];
  sb2[tid] = x[tid]*P.fc_w[tid*2+1];
  __syncthreads();
  for (int s=128;s>0;s>>=1){ if (tid<s){ sb[tid]+=sb[tid+s]; sb2[tid]+=sb2[tid+s]; } __syncthreads(); }
  if (tid==0){
    float l0 = sb[0] + P.fc_b[0];
    float l1 = sb2[0] + P.fc_b[1];
    float m = fmaxf(l0,l1);
    float e0 = expf(l0-m), e1 = expf(l1-m), inv = 1.f/(e0+e1);
    P.out[0] = e0*inv;
    P.out[1] = e1*inv;
  }
}

extern "C" void kernel_launch(void* const* d_in, const int* in_sizes, int n_in,
                              void* d_out, int out_size, void* d_ws, size_t ws_size,
                              hipStream_t stream){
  Params P;
  for (int g=0; g<2; ++g){
    int b = g*5;
    P.g[g].feat  = (const float*)d_in[b+0];
    P.g[g].eidx  = (const int*)d_in[b+1];
    P.g[g].eattr = (const float*)d_in[b+2];
    P.g[g].adj   = (const float*)d_in[b+3];
    P.g[g].n2n   = (const float*)d_in[b+4];
  }
  P.W_h   = (const float*)d_in[10];
  P.W_gat = (const float*)d_in[11];
  P.a_src = (const float*)d_in[12];
  P.a_dst = (const float*)d_in[13];
  P.a_e   = (const float*)d_in[14];
  P.We_gat= (const float*)d_in[15];
  P.W_out = (const float*)d_in[16];
  P.ao_src= (const float*)d_in[17];
  P.ao_dst= (const float*)d_in[18];
  P.ao_e  = (const float*)d_in[19];
  P.We_out= (const float*)d_in[20];
  P.ep1_w = (const float*)d_in[21];
  P.ep1_b = (const float*)d_in[22];
  P.ep2_w = (const float*)d_in[23];
  P.ep2_b = (const float*)d_in[24];
  P.g1_w  = (const float*)d_in[25];
  P.g1_b  = (const float*)d_in[26];
  P.g2_w  = (const float*)d_in[27];
  P.g2_b  = (const float*)d_in[28];
  P.g3_w  = (const float*)d_in[29];
  P.g3_b  = (const float*)d_in[30];
  P.Wih0  = (const float*)d_in[31];
  P.Whh0  = (const float*)d_in[32];
  P.b0    = (const float*)d_in[33];
  P.Wih1  = (const float*)d_in[34];
  P.Whh1  = (const float*)d_in[35];
  P.b1    = (const float*)d_in[36];
  P.fc_w  = (const float*)d_in[37];
  P.fc_b  = (const float*)d_in[38];
  P.out   = (float*)d_out;

  // ---- graph stages ----
  k_zero <<<dim3((TOTF+255)/256 + 1), 256, 0, stream>>>();
  k_pre  <<<dim3((NH*HID+CAT+255)/256), 256, 0, stream>>>(P);
  k_pairs<<<dim3((E+255)/256,2), 256, 0, stream>>>(P);
  k_edoth<<<dim3(NH,2),   256, 0, stream>>>(P);
  k_h0   <<<dim3((2*N*HID+255)/256), 256, 0, stream>>>(P);
  k_gpool_gate<<<dim3(N,2), 256, 0, stream>>>(P, OH0, HID, -1, P.g1_w, P.g1_b);
  k_gpool_out <<<dim3(2),   256, 0, stream>>>(P, OH0, HID, -1, 0);
  k_Wh   <<<dim3(N,NH,2), 128, 0, stream>>>(P);
  k_asad <<<dim3(NH,2),   256, 0, stream>>>(P);
  k_att1 <<<dim3(N,NH,2), 128, 0, stream>>>(P);
  k_edot1<<<dim3(E/TE1,NH,2),128, 0, stream>>>(P);
  k_xw1  <<<dim3(N,2,2),  256, 0, stream>>>(P);
  k_s1   <<<dim3((E+255)/256,2), 256, 0, stream>>>(P);
  k_ns   <<<dim3(1,2),    256, 0, stream>>>(ODEG1, OSS1, ONS1);
  k_gpool_gate<<<dim3(N,2), 256, 0, stream>>>(P, OH1, CAT, ONS1, P.g2_w, P.g2_b);
  k_gpool_out <<<dim3(2),   256, 0, stream>>>(P, OH1, CAT, ONS1, HID);
  k_Wh2  <<<dim3(N,2),    128, 0, stream>>>(P);
  k_asad2<<<dim3(2),      256, 0, stream>>>(P);
  k_att2 <<<dim3(N,2),    128, 0, stream>>>(P);
  k_e2p  <<<dim3(E/TE2,NH,2),128, 0, stream>>>(P);
  k_ew2fin<<<dim3(E/TE2,2),128, 0, stream>>>(P);
  k_xsd2 <<<dim3(2),      256, 0, stream>>>(P);
  k_s2   <<<dim3((E+255)/256,2), 256, 0, stream>>>(P);
  k_ns   <<<dim3(1,2),    256, 0, stream>>>(ODEG2, OSS2, ONS2);
  k_gpool_gate<<<dim3(N,2), 256, 0, stream>>>(P, OH2B, OUTD, ONS2, P.g3_w, P.g3_b);
  k_gpool_out <<<dim3(2),   256, 0, stream>>>(P, OH2B, OUTD, ONS2, HID+CAT);

  // ---- LSTM stack + classifier ----
  k_lstm_xg <<<dim3(512), 256, 0, stream>>>(P, 0);
  k_lstm_rec<<<dim3(2),   512, 0, stream>>>(P, 0);
  k_lstm_xg <<<dim3(512), 256, 0, stream>>>(P, 1);
  k_lstm_rec<<<dim3(2),   512, 0, stream>>>(P, 1);
  k_final<<<dim3(1), 256, 0, stream>>>(P);
}

// Round 10
// 690.005 us; speedup vs baseline: 2.6335x; 1.0236x over previous
//
#include <hip/hip_runtime.h>
#include <math.h>

#define DI static __device__ __forceinline__

DI float eluf(float x){ return x > 0.f ? x : expm1f(x); }
DI float lreluf(float x){ return x > 0.f ? x : 0.2f*x; }
DI float sigmf(float x){ return 1.f/(1.f+expf(-x)); }

constexpr int N=200, E=3200, HID=64, NH=16, OUTD=128, CAT=2048, SEQD=2240;

// ---- per-graph f32 scratch offsets (in floats) ----
constexpr int OH0   = 0;
constexpr int OWH   = OH0 + N*HID;
constexpr int OASN  = OWH + NH*N*OUTD;
constexpr int OADN  = OASN + NH*N;
constexpr int OH1   = OADN + NH*N;
constexpr int OXW1  = OH1 + N*CAT;
constexpr int OXW2  = OXW1 + 256;
constexpr int OEW1  = OXW2 + 256;
constexpr int OS1   = OEW1 + E;
constexpr int ODEG1 = OS1 + E;
constexpr int OSS1  = ODEG1 + 256;
constexpr int ONS1  = OSS1 + 256;
constexpr int OWH2  = ONS1 + 256;
constexpr int OAS2  = OWH2 + N*OUTD;
constexpr int OAD2  = OAS2 + 256;
constexpr int OEWV  = OAD2 + 256;
constexpr int OH2B  = OEWV + E;
constexpr int OXS2  = OH2B + N*OUTD;
constexpr int OXD2  = OXS2 + 256;
constexpr int OEW2  = OXD2 + 256;
constexpr int OS2   = OEW2 + E;
constexpr int ODEG2 = OS2 + E;
constexpr int OSS2  = ODEG2 + 256;
constexpr int ONS2  = OSS2 + 256;
constexpr int OGATE = ONS2 + 256;
constexpr int PGF   = OGATE + 256;
constexpr int GLOBF = 10624;
constexpr int TOTF  = GLOBF + 2*PGF;

// ---- static device scratch: independent of ws_size ----
__device__ float G_F[TOTF];
__device__ float G_E2PART[(size_t)NH*2*E*OUTD];   // per-head e2 partials (52 MB, no zero needed)
__device__ float G_EDOTH[2*NH*E];                  // eattr@weae per (g,h,e)
__device__ int   G_PIDX[2*N*N];

DI float* gf(int g){ return G_F + GLOBF + (size_t)g*PGF; }
DI float* gwe_ae(){ return G_F; }
DI float* gv_e(){ return G_F + 1024; }
DI float* gy0(){ return G_F + 3072; }
DI float* gy1(){ return G_F + 3584; }
DI float* gxseq(){ return G_F + 4096; }
DI float* gxg(){ return G_F + 8576; }
DI int*   gpidx(int g){ return G_PIDX + g*N*N; }

struct GraphIn {
  const float *feat, *eattr, *adj, *n2n;
  const int   *eidx;
};

struct Params {
  GraphIn g[2];
  const float *W_h, *W_gat, *a_src, *a_dst, *a_e, *We_gat;
  const float *W_out, *ao_src, *ao_dst, *ao_e, *We_out;
  const float *ep1_w, *ep1_b, *ep2_w, *ep2_b;
  const float *g1_w, *g1_b, *g2_w, *g2_b, *g3_w, *g3_b;
  const float *Wih0, *Whh0, *b0, *Wih1, *Whh1, *b1, *fc_w, *fc_b;
  float *out;
};

// ---------------- zero scratch; pairIdx=-1 ----------------
__global__ void k_zero(){
  int idx = blockIdx.x*256 + threadIdx.x;
  if (idx < TOTF) G_F[idx] = 0.f;
  if (idx < 2*N*N) G_PIDX[idx] = -1;
}

// ---------------- precontract We@a_e vectors ----------------
__global__ void k_pre(Params P){
  int idx = blockIdx.x*256 + threadIdx.x;
  if (idx < NH*HID){
    int h = idx/HID, c = idx%HID;
    const float* W = P.We_gat + (size_t)(h*HID + c)*OUTD;
    const float* a = P.a_e + h*OUTD;
    float acc = 0.f;
    for (int o=0;o<OUTD;o++) acc += W[o]*a[o];
    gwe_ae()[idx] = acc;
  } else if (idx < NH*HID + CAT){
    int c = idx - NH*HID;
    const float* W = P.We_out + (size_t)c*OUTD;
    float acc = 0.f;
    for (int o=0;o<OUTD;o++) acc += W[o]*P.ao_e[o];
    gv_e()[c] = acc;
  }
}

// ---- EDOTH[g][h][e] = eattr[e] . weae[h] ----
__global__ void k_edoth(Params P){
  int h = blockIdx.x, g = blockIdx.y;
  const float* weae = gwe_ae() + h*HID;
  for (int e = threadIdx.x; e < E; e += 256){
    const float* row = P.g[g].eattr + (size_t)e*HID;
    float acc = 0.f;
    for (int c=0;c<HID;c++) acc += row[c]*weae[c];
    G_EDOTH[((size_t)g*NH+h)*E + e] = acc;
  }
}

// ---------------- h0 = elu(feat @ W_h) ----------------
__global__ void k_h0(Params P){
  int idx = blockIdx.x*256 + threadIdx.x;
  if (idx >= 2*N*HID) return;
  int g = idx/(N*HID), r = idx%(N*HID), n = r/HID, c = r%HID;
  const float* feat = P.g[g].feat;
  float acc = 0.f;
  for (int k=0;k<HID;k++) acc += feat[n*HID+k]*P.W_h[k*HID+c];
  gf(g)[OH0 + n*HID + c] = eluf(acc);
}

// ---------------- Wh[h] = h0 @ W_gat[h] ----------------
__global__ void k_Wh(Params P){
  int n = blockIdx.x, h = blockIdx.y, g = blockIdx.z, o = threadIdx.x;
  __shared__ float hs[HID];
  float* f = gf(g);
  if (o < HID) hs[o] = f[OH0 + n*HID + o];
  __syncthreads();
  const float* W = P.W_gat + (size_t)h*HID*OUTD + o;
  float acc = 0.f;
  for (int c=0;c<HID;c++) acc += hs[c]*W[(size_t)c*OUTD];
  f[OWH + ((size_t)h*N + n)*OUTD + o] = acc;
}

// ---------------- asn/adn = Wh @ a_src / a_dst ----------------
__global__ void k_asad(Params P){
  int h = blockIdx.x, g = blockIdx.y;
  float* f = gf(g);
  for (int n = threadIdx.x; n < N; n += 256){
    const float* wh = f + OWH + ((size_t)h*N + n)*OUTD;
    float s=0.f, d=0.f;
    for (int o=0;o<OUTD;o++){
      float v = wh[o];
      s += v*P.a_src[h*OUTD+o];
      d += v*P.a_dst[h*OUTD+o];
    }
    f[OASN + h*N + n] = s;
    f[OADN + h*N + n] = d;
  }
}

// ---------------- GAT layer 1: edge term via EDOTH lookup ----------------
__global__ void k_att1(Params P){
  int n = blockIdx.x, h = blockIdx.y, g = blockIdx.z, tid = threadIdx.x;
  __shared__ float z[N];
  __shared__ float red[128];
  float* f = gf(g);
  const float* adj = P.g[g].adj;
  const int* pidx = gpidx(g);
  const float* edoth = G_EDOTH + ((size_t)g*NH + h)*E;
  float asn = f[OASN + h*N + n];
  const float* adn = f + OADN + h*N;
  for (int j = tid; j < N; j += 128){
    float a = adj[n*N + j];
    float zz;
    if (a > 0.f){
      int p = pidx[n*N + j];
      float ee = (p >= 0) ? edoth[p] : 0.f;
      zz = lreluf(asn + adn[j] + ee);
    } else zz = -1e9f;
    z[j] = zz;
  }
  __syncthreads();
  float m = -3e38f;
  for (int j = tid; j < N; j += 128) m = fmaxf(m, z[j]);
  red[tid] = m; __syncthreads();
  for (int s=64;s>0;s>>=1){ if (tid<s) red[tid]=fmaxf(red[tid],red[tid+s]); __syncthreads(); }
  m = red[0]; __syncthreads();
  float ssum = 0.f;
  for (int j = tid; j < N; j += 128){ float e = expf(z[j]-m); z[j]=e; ssum += e; }
  red[tid] = ssum; __syncthreads();
  for (int s=64;s>0;s>>=1){ if (tid<s) red[tid]+=red[tid+s]; __syncthreads(); }
  float inv = 1.f/red[0]; __syncthreads();
  const float* wh = f + OWH + (size_t)h*N*OUTD;
  float acc = 0.f;
  for (int j=0;j<N;j++){
    float w = z[j];
    if (w != 0.f) acc += w * wh[(size_t)j*OUTD + tid];
  }
  f[OH1 + (size_t)n*CAT + h*OUTD + tid] = eluf(acc*inv);
}

// ---- edge dots, head-split; es read uniform from global (scalar path) ----
constexpr int TE1 = 8;
__global__ __launch_bounds__(128, 4) void k_edot1(Params P){
  int e0 = blockIdx.x*TE1, h = blockIdx.y, g = blockIdx.z, tid = threadIdx.x; // 128 thr
  __shared__ float lred[2][TE1][2];
  const float* __restrict__ ea = P.g[g].eattr + (size_t)e0*HID;
  const float* __restrict__ W = P.We_gat + (size_t)(h*HID)*OUTD + tid;
  float t[TE1];
  for (int e=0;e<TE1;e++) t[e]=0.f;
  for (int c=0;c<HID;c++){
    float w = W[(size_t)c*OUTD];
    for (int e=0;e<TE1;e++) t[e] += ea[e*HID+c]*w;
  }
  float w1 = P.ep1_w[2*CAT + h*OUTD + tid];
  float wv = gv_e()[h*OUTD + tid];
  int lane = tid & 63, wvi = tid >> 6;
  for (int e=0;e<TE1;e++){
    float u = eluf(t[e]);
    float v1 = u*w1, v2 = u*wv;
    for (int off=32;off>0;off>>=1){ v1 += __shfl_down(v1,off); v2 += __shfl_down(v2,off); }
    if (lane==0){ lred[wvi][e][0]=v1; lred[wvi][e][1]=v2; }
  }
  __syncthreads();
  if (tid < TE1*2){
    int e = tid>>1, which = tid&1;
    float s = lred[0][e][which]+lred[1][e][which];
    atomicAdd(&gf(g)[(which? OEWV:OEW1) + e0+e], s);
  }
}

// ---------------- pool1 node dots ----------------
__global__ void k_xw1(Params P){
  int n = blockIdx.x, wch = blockIdx.y, g = blockIdx.z, tid = threadIdx.x;
  __shared__ float sb[256];
  float* f = gf(g);
  const float* x = f + OH1 + (size_t)n*CAT;
  const float* w = P.ep1_w + wch*CAT;
  float acc = 0.f;
  for (int c = tid; c < CAT; c += 256) acc += x[c]*w[c];
  sb[tid] = acc; __syncthreads();
  for (int s=128;s>0;s>>=1){ if (tid<s) sb[tid]+=sb[tid+s]; __syncthreads(); }
  if (tid==0) f[(wch? OXW2:OXW1) + n] = sb[0];
}

// ---------------- pool1 edge scores + segment sums ----------------
__global__ void k_s1(Params P){
  int e = blockIdx.x*256 + threadIdx.x, g = blockIdx.y;
  if (e >= E) return;
  float* f = gf(g);
  const int* ei = P.g[g].eidx;
  int s = ei[e], d = ei[E+e];
  float v = sigmf(f[OXW1+s] + f[OXW2+d] + f[OEW1+e] + P.ep1_b[0]);
  f[OS1+e] = v;
  atomicAdd(&f[OSS1+s], v);
  atomicAdd(&f[ODEG1+s], 1.f);
}

__global__ void k_ns(int odeg, int oss, int ons){
  int g = blockIdx.y, n = threadIdx.x;
  if (n < N){ float* f = gf(g); f[ons+n] = f[oss+n]/(f[odeg+n]+1e-6f); }
}

// ---------------- pairIdx: last edge wins ----------------
__global__ void k_pairs(Params P){
  int e = blockIdx.x*256 + threadIdx.x, g = blockIdx.y;
  if (e >= E) return;
  const int* ei = P.g[g].eidx;
  atomicMax(&gpidx(g)[ei[e]*N + ei[E+e]], e);
}

// ---------------- global attention pool ----------------
__global__ void k_gpool_gate(Params P, int xoff, int D, int scaleoff, const float* w, const float* b){
  int n = blockIdx.x, g = blockIdx.y, tid = threadIdx.x;
  __shared__ float sb[256];
  float* f = gf(g);
  const float* x = f + xoff + (size_t)n*D;
  float acc = 0.f;
  for (int c = tid; c < D; c += 256) acc += x[c]*w[c];
  sb[tid] = acc; __syncthreads();
  for (int s=128;s>0;s>>=1){ if (tid<s) sb[tid]+=sb[tid+s]; __syncthreads(); }
  if (tid==0){
    float sc = scaleoff>=0 ? f[scaleoff+n] : 1.f;
    f[OGATE+n] = sigmf(sb[0]*sc + b[0]);
  }
}

__global__ void k_gpool_out(Params P, int xoff, int D, int scaleoff, int outoff){
  int g = blockIdx.x, tid = threadIdx.x;
  __shared__ float att[N];
  __shared__ float sb[256];
  float* f = gf(g);
  float m = -3e38f;
  for (int n = tid; n < N; n += 256) m = fmaxf(m, f[OGATE+n]);
  sb[tid] = m; __syncthreads();
  for (int s=128;s>0;s>>=1){ if (tid<s) sb[tid]=fmaxf(sb[tid],sb[tid+s]); __syncthreads(); }
  m = sb[0]; __syncthreads();
  float ss = 0.f;
  for (int n = tid; n < N; n += 256){ float e = expf(f[OGATE+n]-m); att[n]=e; ss += e; }
  sb[tid] = ss; __syncthreads();
  for (int s=128;s>0;s>>=1){ if (tid<s) sb[tid]+=sb[tid+s]; __syncthreads(); }
  float inv = 1.f/sb[0]; __syncthreads();
  for (int n = tid; n < N; n += 256){
    float sc = scaleoff>=0 ? f[scaleoff+n] : 1.f;
    att[n] *= inv*sc;
  }
  __syncthreads();
  const float* x = f + xoff;
  for (int c = tid; c < D; c += 256){
    float acc = 0.f;
    for (int n=0;n<N;n++) acc += att[n]*x[(size_t)n*D + c];
    gxseq()[g*SEQD + outoff + c] = acc;
  }
}

// ---------------- Wh2 = (h1cat @ W_out) * ns1 ----------------
__global__ void k_Wh2(Params P){
  int n = blockIdx.x, g = blockIdx.y, tid = threadIdx.x;
  __shared__ float hrow[128];
  float* f = gf(g);
  const float* x = f + OH1 + (size_t)n*CAT;
  float ns = f[ONS1+n];
  float acc = 0.f;
  for (int c0=0;c0<CAT;c0+=128){
    __syncthreads();
    hrow[tid] = x[c0+tid];
    __syncthreads();
    const float* W = P.W_out + (size_t)c0*OUTD + tid;
    for (int cc=0;cc<128;cc++) acc += hrow[cc]*W[(size_t)cc*OUTD];
  }
  f[OWH2 + (size_t)n*OUTD + tid] = acc*ns;
}

__global__ void k_asad2(Params P){
  int g = blockIdx.x;
  float* f = gf(g);
  for (int n = threadIdx.x; n < N; n += 256){
    const float* wh = f + OWH2 + (size_t)n*OUTD;
    float s=0.f, d=0.f;
    for (int o=0;o<OUTD;o++){
      float v = wh[o];
      s += v*P.ao_src[o];
      d += v*P.ao_dst[o];
    }
    f[OAS2+n]=s; f[OAD2+n]=d;
  }
}

// ---------------- GAT layer 2 ----------------
__global__ void k_att2(Params P){
  int n = blockIdx.x, g = blockIdx.y, tid = threadIdx.x;
  __shared__ float z[N];
  __shared__ float red[128];
  float* f = gf(g);
  const float* adj = P.g[g].adj;
  const int* pidx = gpidx(g);
  float asn = f[OAS2+n];
  const float* adn = f + OAD2;
  for (int j = tid; j < N; j += 128){
    float a = adj[n*N + j];
    float zz;
    if (a > 0.f){
      int p = pidx[n*N + j];
      float ee = (p >= 0) ? f[OEWV+p]*f[OS1+p] : 0.f;
      zz = lreluf(asn + adn[j] + ee);
    } else zz = -1e9f;
    z[j] = zz;
  }
  __syncthreads();
  float m = -3e38f;
  for (int j = tid; j < N; j += 128) m = fmaxf(m, z[j]);
  red[tid] = m; __syncthreads();
  for (int s=64;s>0;s>>=1){ if (tid<s) red[tid]=fmaxf(red[tid],red[tid+s]); __syncthreads(); }
  m = red[0]; __syncthreads();
  float ssum = 0.f;
  for (int j = tid; j < N; j += 128){ float e = expf(z[j]-m); z[j]=e; ssum += e; }
  red[tid] = ssum; __syncthreads();
  for (int s=64;s>0;s>>=1){ if (tid<s) red[tid]+=red[tid+s]; __syncthreads(); }
  float inv = 1.f/red[0]; __syncthreads();
  const float* wh = f + OWH2;
  float acc = 0.f;
  for (int j=0;j<N;j++){
    float w = z[j];
    if (w != 0.f) acc += w * wh[(size_t)j*OUTD + tid];
  }
  f[OH2B + (size_t)n*OUTD + tid] = acc*inv;
}

// ---- e2 partial: es uniform-global loop1; b128 tcol reads loop2 ----
constexpr int TE2 = 16;
__global__ __launch_bounds__(128, 4) void k_e2p(Params P){
  int e0 = blockIdx.x*TE2, h = blockIdx.y, g = blockIdx.z, tid = threadIdx.x; // 128 thr
  __shared__ float tcol[TE2][OUTD];
  const float* __restrict__ ea = P.g[g].eattr + (size_t)e0*HID;
  const float* __restrict__ W1 = P.We_gat + (size_t)(h*HID)*OUTD + tid;
  float t[TE2];
  for (int e=0;e<TE2;e++) t[e]=0.f;
  for (int c=0;c<HID;c++){
    float w = W1[(size_t)c*OUTD];
    for (int e=0;e<TE2;e++) t[e] += ea[e*HID+c]*w;
  }
  for (int e=0;e<TE2;e++) tcol[e][tid] = eluf(t[e]);
  __syncthreads();
  float acc[TE2];
  for (int e=0;e<TE2;e++) acc[e]=0.f;
  const float* __restrict__ W2 = P.We_out + (size_t)(h*OUTD)*OUTD + tid;
  for (int o4=0;o4<OUTD/4;o4++){
    float w0 = W2[(size_t)(4*o4+0)*OUTD];
    float w1 = W2[(size_t)(4*o4+1)*OUTD];
    float w2 = W2[(size_t)(4*o4+2)*OUTD];
    float w3 = W2[(size_t)(4*o4+3)*OUTD];
    for (int e=0;e<TE2;e++){
      float4 tv = ((const float4*)tcol[e])[o4];
      acc[e] += tv.x*w0 + tv.y*w1 + tv.z*w2 + tv.w*w3;
    }
  }
  float* dst = G_E2PART + (((size_t)h*2 + g)*E + e0)*OUTD + tid;
  for (int e=0;e<TE2;e++) dst[(size_t)e*OUTD] = acc[e];
}

// ---- finish: sum 16 head-partials, elu, dot ep2_w ----
__global__ void k_ew2fin(Params P){
  int e0 = blockIdx.x*TE2, g = blockIdx.y, tid = threadIdx.x;  // 128 thr
  __shared__ float lred[2][TE2];
  float* f = gf(g);
  float w2 = P.ep2_w[2*OUTD + tid];
  int lane = tid & 63, wvi = tid >> 6;
  for (int e=0;e<TE2;e++){
    const float* src = G_E2PART + ((size_t)g*E + e0 + e)*OUTD + tid;
    float a = 0.f;
    for (int h=0;h<NH;h++) a += src[(size_t)h*2*E*OUTD];
    float v = eluf(f[OS1+e0+e]*a) * w2;
    for (int off=32;off>0;off>>=1) v += __shfl_down(v,off);
    if (lane==0) lred[wvi][e]=v;
  }
  __syncthreads();
  if (tid < TE2) f[OEW2+e0+tid] = lred[0][tid]+lred[1][tid];
}

// ---------------- pool2 node dots ----------------
__global__ void k_xsd2(Params P){
  int g = blockIdx.x;
  float* f = gf(g);
  for (int n = threadIdx.x; n < N; n += 256){
    const float* x = f + OH2B + (size_t)n*OUTD;
    float s=0.f, d=0.f;
    for (int k=0;k<OUTD;k++){
      float v = x[k];
      s += v*P.ep2_w[k];
      d += v*P.ep2_w[OUTD+k];
    }
    f[OXS2+n]=s; f[OXD2+n]=d;
  }
}

__global__ void k_s2(Params P){
  int e = blockIdx.x*256 + threadIdx.x, g = blockIdx.y;
  if (e >= E) return;
  float* f = gf(g);
  const int* ei = P.g[g].eidx;
  int s = ei[e], d = ei[E+e];
  float v = sigmf(f[OXS2+s] + f[OXD2+d] + f[OEW2+e] + P.ep2_b[0]);
  f[OS2+e] = v;
  atomicAdd(&f[OSS2+s], v);
  atomicAdd(&f[ODEG2+s], 1.f);
}

// ---- LSTM input projection ----
__global__ void k_lstm_xg(Params P, int layer){
  int gid = blockIdx.x*4 + (threadIdx.x>>6);
  int lane = threadIdx.x & 63;
  int t = gid >> 10;
  int rem = gid & 1023;
  int d = rem >> 9;
  int gate = rem & 511;
  const float* Wih = layer ? P.Wih1 : P.Wih0;
  const float* bb  = layer ? P.b1   : P.b0;
  const float* xin = layer ? gy0()  : gxseq();
  int Din = layer ? 256 : SEQD;
  const float* x = xin + t*Din;
  const float* Wr = Wih + ((size_t)d*512 + gate)*Din;
  float acc = 0.f;
  for (int k=lane; k<Din; k+=64) acc += x[k]*Wr[k];
  for (int off=32; off>0; off>>=1) acc += __shfl_down(acc, off);
  if (lane==0) gxg()[(t*2 + d)*512 + gate] = acc + bb[d*512 + gate];
}

// ---- LSTM recurrence only ----
__global__ void k_lstm_rec(Params P, int layer){
  int d = blockIdx.x, tid = threadIdx.x;
  const float* Whh = layer ? P.Whh1 : P.Whh0;
  float* yout = layer ? gy1() : gy0();
  __shared__ float h[128], c[128], gbuf[512];
  if (tid < 128){ h[tid]=0.f; c[tid]=0.f; }
  __syncthreads();
  for (int s=0;s<2;s++){
    int t = (d==0) ? s : 1-s;
    float acc = gxg()[(t*2 + d)*512 + tid];
    const float* Ur = Whh + ((size_t)d*512 + tid)*128;
    for (int k=0;k<128;k++) acc += h[k]*Ur[k];
    gbuf[tid] = acc;
    __syncthreads();
    if (tid < 128){
      float ii = sigmf(gbuf[tid]);
      float ff = sigmf(gbuf[128+tid]);
      float gg = tanhf(gbuf[256+tid]);
      float oo = sigmf(gbuf[384+tid]);
      float cn = ff*c[tid] + ii*gg;
      c[tid] = cn;
      float hn = oo*tanhf(cn);
      h[tid] = hn;
      yout[t*256 + d*128 + tid] = hn;
    }
    __syncthreads();
  }
}

// ---------------- final FC + softmax ----------------
__global__ void k_final(Params P){
  int tid = threadIdx.x;
  __shared__ float sb[256], sb2[256];
  const float* x = gy1() + 256;
  sb[tid]  = x[tid]*P.fc_w[tid*2+0];
  sb2[tid] = x[tid]*P.fc_w[tid*2+1];
  __syncthreads();
  for (int s=128;s>0;s>>=1){ if (tid<s){ sb[tid]+=sb[tid+s]; sb2[tid]+=sb2[tid+s]; } __syncthreads(); }
  if (tid==0){
    float l0 = sb[0] + P.fc_b[0];
    float l1 = sb2[0] + P.fc_b[1];
    float m = fmaxf(l0,l1);
    float e0 = expf(l0-m), e1 = expf(l1-m), inv = 1.f/(e0+e1);
    P.out[0] = e0*inv;
    P.out[1] = e1*inv;
  }
}

extern "C" void kernel_launch(void* const* d_in, const int* in_sizes, int n_in,
                              void* d_out, int out_size, void* d_ws, size_t ws_size,
                              hipStream_t stream){
  Params P;
  for (int g=0; g<2; ++g){
    int b = g*5;
    P.g[g].feat  = (const float*)d_in[b+0];
    P.g[g].eidx  = (const int*)d_in[b+1];
    P.g[g].eattr = (const float*)d_in[b+2];
    P.g[g].adj   = (const float*)d_in[b+3];
    P.g[g].n2n   = (const float*)d_in[b+4];
  }
  P.W_h   = (const float*)d_in[10];
  P.W_gat = (const float*)d_in[11];
  P.a_src = (const float*)d_in[12];
  P.a_dst = (const float*)d_in[13];
  P.a_e   = (const float*)d_in[14];
  P.We_gat= (const float*)d_in[15];
  P.W_out = (const float*)d_in[16];
  P.ao_src= (const float*)d_in[17];
  P.ao_dst= (const float*)d_in[18];
  P.ao_e  = (const float*)d_in[19];
  P.We_out= (const float*)d_in[20];
  P.ep1_w = (const float*)d_in[21];
  P.ep1_b = (const float*)d_in[22];
  P.ep2_w = (const float*)d_in[23];
  P.ep2_b = (const float*)d_in[24];
  P.g1_w  = (const float*)d_in[25];
  P.g1_b  = (const float*)d_in[26];
  P.g2_w  = (const float*)d_in[27];
  P.g2_b  = (const float*)d_in[28];
  P.g3_w  = (const float*)d_in[29];
  P.g3_b  = (const float*)d_in[30];
  P.Wih0  = (const float*)d_in[31];
  P.Whh0  = (const float*)d_in[32];
  P.b0    = (const float*)d_in[33];
  P.Wih1  = (const float*)d_in[34];
  P.Whh1  = (const float*)d_in[35];
  P.b1    = (const float*)d_in[36];
  P.fc_w  = (const float*)d_in[37];
  P.fc_b  = (const float*)d_in[38];
  P.out   = (float*)d_out;

  // ---- graph stages ----
  k_zero <<<dim3((TOTF+255)/256 + 1), 256, 0, stream>>>();
  k_pre  <<<dim3((NH*HID+CAT+255)/256), 256, 0, stream>>>(P);
  k_pairs<<<dim3((E+255)/256,2), 256, 0, stream>>>(P);
  k_edoth<<<dim3(NH,2),   256, 0, stream>>>(P);
  k_h0   <<<dim3((2*N*HID+255)/256), 256, 0, stream>>>(P);
  k_gpool_gate<<<dim3(N,2), 256, 0, stream>>>(P, OH0, HID, -1, P.g1_w, P.g1_b);
  k_gpool_out <<<dim3(2),   256, 0, stream>>>(P, OH0, HID, -1, 0);
  k_Wh   <<<dim3(N,NH,2), 128, 0, stream>>>(P);
  k_asad <<<dim3(NH,2),   256, 0, stream>>>(P);
  k_att1 <<<dim3(N,NH,2), 128, 0, stream>>>(P);
  k_edot1<<<dim3(E/TE1,NH,2),128, 0, stream>>>(P);
  k_xw1  <<<dim3(N,2,2),  256, 0, stream>>>(P);
  k_s1   <<<dim3((E+255)/256,2), 256, 0, stream>>>(P);
  k_ns   <<<dim3(1,2),    256, 0, stream>>>(ODEG1, OSS1, ONS1);
  k_gpool_gate<<<dim3(N,2), 256, 0, stream>>>(P, OH1, CAT, ONS1, P.g2_w, P.g2_b);
  k_gpool_out <<<dim3(2),   256, 0, stream>>>(P, OH1, CAT, ONS1, HID);
  k_Wh2  <<<dim3(N,2),    128, 0, stream>>>(P);
  k_asad2<<<dim3(2),      256, 0, stream>>>(P);
  k_att2 <<<dim3(N,2),    128, 0, stream>>>(P);
  k_e2p  <<<dim3(E/TE2,NH,2),128, 0, stream>>>(P);
  k_ew2fin<<<dim3(E/TE2,2),128, 0, stream>>>(P);
  k_xsd2 <<<dim3(2),      256, 0, stream>>>(P);
  k_s2   <<<dim3((E+255)/256,2), 256, 0, stream>>>(P);
  k_ns   <<<dim3(1,2),    256, 0, stream>>>(ODEG2, OSS2, ONS2);
  k_gpool_gate<<<dim3(N,2), 256, 0, stream>>>(P, OH2B, OUTD, ONS2, P.g3_w, P.g3_b);
  k_gpool_out <<<dim3(2),   256, 0, stream>>>(P, OH2B, OUTD, ONS2, HID+CAT);

  // ---- LSTM stack + classifier ----
  k_lstm_xg <<<dim3(512), 256, 0, stream>>>(P, 0);
  k_lstm_rec<<<dim3(2),   512, 0, stream>>>(P, 0);
  k_lstm_xg <<<dim3(512), 256, 0, stream>>>(P, 1);
  k_lstm_rec<<<dim3(2),   512, 0, stream>>>(P, 1);
  k_final<<<dim3(1), 256, 0, stream>>>(P);
}

// Round 11
// 633.661 us; speedup vs baseline: 2.8677x; 1.0889x over previous
//
#include <hip/hip_runtime.h>
#include <math.h>

#define DI static __device__ __forceinline__

DI float eluf(float x){ return x > 0.f ? x : expm1f(x); }
DI float lreluf(float x){ return x > 0.f ? x : 0.2f*x; }
DI float sigmf(float x){ return 1.f/(1.f+expf(-x)); }

constexpr int N=200, E=3200, HID=64, NH=16, OUTD=128, CAT=2048, SEQD=2240;

// ---- per-graph f32 scratch offsets (in floats) ----
constexpr int OH0   = 0;
constexpr int OWH   = OH0 + N*HID;
constexpr int OASN  = OWH + NH*N*OUTD;
constexpr int OADN  = OASN + NH*N;
constexpr int OH1   = OADN + NH*N;
constexpr int OXW1  = OH1 + N*CAT;
constexpr int OXW2  = OXW1 + 256;
constexpr int OEW1  = OXW2 + 256;
constexpr int OS1   = OEW1 + E;
constexpr int ODEG1 = OS1 + E;
constexpr int OSS1  = ODEG1 + 256;
constexpr int ONS1  = OSS1 + 256;
constexpr int OWH2  = ONS1 + 256;
constexpr int OAS2  = OWH2 + N*OUTD;
constexpr int OAD2  = OAS2 + 256;
constexpr int OEWV  = OAD2 + 256;
constexpr int OH2B  = OEWV + E;
constexpr int OXS2  = OH2B + N*OUTD;
constexpr int OXD2  = OXS2 + 256;
constexpr int OEW2  = OXD2 + 256;
constexpr int OS2   = OEW2 + E;
constexpr int ODEG2 = OS2 + E;
constexpr int OSS2  = ODEG2 + 256;
constexpr int ONS2  = OSS2 + 256;
constexpr int OGATE = ONS2 + 256;
constexpr int PGF   = OGATE + 256;
constexpr int GLOBF = 10624;
constexpr int TOTF  = GLOBF + 2*PGF;

// ---- static device scratch: independent of ws_size ----
__device__ float G_F[TOTF];
__device__ float G_E2PART[(size_t)NH*2*E*OUTD];   // per-head e2 partials (52 MB, no zero needed)
__device__ float G_EDOTH[2*NH*E];                  // eattr@weae per (g,h,e)
__device__ int   G_PIDX[2*N*N];

DI float* gf(int g){ return G_F + GLOBF + (size_t)g*PGF; }
DI float* gwe_ae(){ return G_F; }
DI float* gv_e(){ return G_F + 1024; }
DI float* gy0(){ return G_F + 3072; }
DI float* gy1(){ return G_F + 3584; }
DI float* gxseq(){ return G_F + 4096; }
DI float* gxg(){ return G_F + 8576; }
DI int*   gpidx(int g){ return G_PIDX + g*N*N; }

struct GraphIn {
  const float *feat, *eattr, *adj, *n2n;
  const int   *eidx;
};

struct Params {
  GraphIn g[2];
  const float *W_h, *W_gat, *a_src, *a_dst, *a_e, *We_gat;
  const float *W_out, *ao_src, *ao_dst, *ao_e, *We_out;
  const float *ep1_w, *ep1_b, *ep2_w, *ep2_b;
  const float *g1_w, *g1_b, *g2_w, *g2_b, *g3_w, *g3_b;
  const float *Wih0, *Whh0, *b0, *Wih1, *Whh1, *b1, *fc_w, *fc_b;
  float *out;
};

// ---------------- zero scratch; pairIdx=-1 ----------------
__global__ void k_zero(){
  int idx = blockIdx.x*256 + threadIdx.x;
  if (idx < TOTF) G_F[idx] = 0.f;
  if (idx < 2*N*N) G_PIDX[idx] = -1;
}

// ---------------- precontract We@a_e vectors ----------------
__global__ void k_pre(Params P){
  int idx = blockIdx.x*256 + threadIdx.x;
  if (idx < NH*HID){
    int h = idx/HID, c = idx%HID;
    const float* W = P.We_gat + (size_t)(h*HID + c)*OUTD;
    const float* a = P.a_e + h*OUTD;
    float acc = 0.f;
    for (int o=0;o<OUTD;o++) acc += W[o]*a[o];
    gwe_ae()[idx] = acc;
  } else if (idx < NH*HID + CAT){
    int c = idx - NH*HID;
    const float* W = P.We_out + (size_t)c*OUTD;
    float acc = 0.f;
    for (int o=0;o<OUTD;o++) acc += W[o]*P.ao_e[o];
    gv_e()[c] = acc;
  }
}

// ---- EDOTH[g][h][e] = eattr[e] . weae[h] ----
__global__ void k_edoth(Params P){
  int h = blockIdx.x, g = blockIdx.y;
  const float* weae = gwe_ae() + h*HID;
  for (int e = threadIdx.x; e < E; e += 256){
    const float* row = P.g[g].eattr + (size_t)e*HID;
    float acc = 0.f;
    for (int c=0;c<HID;c++) acc += row[c]*weae[c];
    G_EDOTH[((size_t)g*NH+h)*E + e] = acc;
  }
}

// ---------------- h0 = elu(feat @ W_h) ----------------
__global__ void k_h0(Params P){
  int idx = blockIdx.x*256 + threadIdx.x;
  if (idx >= 2*N*HID) return;
  int g = idx/(N*HID), r = idx%(N*HID), n = r/HID, c = r%HID;
  const float* feat = P.g[g].feat;
  float acc = 0.f;
  for (int k=0;k<HID;k++) acc += feat[n*HID+k]*P.W_h[k*HID+c];
  gf(g)[OH0 + n*HID + c] = eluf(acc);
}

// ---------------- Wh[h] = h0 @ W_gat[h] ----------------
__global__ void k_Wh(Params P){
  int n = blockIdx.x, h = blockIdx.y, g = blockIdx.z, o = threadIdx.x;
  __shared__ float hs[HID];
  float* f = gf(g);
  if (o < HID) hs[o] = f[OH0 + n*HID + o];
  __syncthreads();
  const float* W = P.W_gat + (size_t)h*HID*OUTD + o;
  float acc = 0.f;
  for (int c=0;c<HID;c++) acc += hs[c]*W[(size_t)c*OUTD];
  f[OWH + ((size_t)h*N + n)*OUTD + o] = acc;
}

// ---------------- asn/adn = Wh @ a_src / a_dst ----------------
__global__ void k_asad(Params P){
  int h = blockIdx.x, g = blockIdx.y;
  float* f = gf(g);
  for (int n = threadIdx.x; n < N; n += 256){
    const float* wh = f + OWH + ((size_t)h*N + n)*OUTD;
    float s=0.f, d=0.f;
    for (int o=0;o<OUTD;o++){
      float v = wh[o];
      s += v*P.a_src[h*OUTD+o];
      d += v*P.a_dst[h*OUTD+o];
    }
    f[OASN + h*N + n] = s;
    f[OADN + h*N + n] = d;
  }
}

// ---------------- GAT layer 1: edge term via EDOTH lookup ----------------
__global__ void k_att1(Params P){
  int n = blockIdx.x, h = blockIdx.y, g = blockIdx.z, tid = threadIdx.x;
  __shared__ float z[N];
  __shared__ float red[128];
  float* f = gf(g);
  const float* adj = P.g[g].adj;
  const int* pidx = gpidx(g);
  const float* edoth = G_EDOTH + ((size_t)g*NH + h)*E;
  float asn = f[OASN + h*N + n];
  const float* adn = f + OADN + h*N;
  for (int j = tid; j < N; j += 128){
    float a = adj[n*N + j];
    float zz;
    if (a > 0.f){
      int p = pidx[n*N + j];
      float ee = (p >= 0) ? edoth[p] : 0.f;
      zz = lreluf(asn + adn[j] + ee);
    } else zz = -1e9f;
    z[j] = zz;
  }
  __syncthreads();
  float m = -3e38f;
  for (int j = tid; j < N; j += 128) m = fmaxf(m, z[j]);
  red[tid] = m; __syncthreads();
  for (int s=64;s>0;s>>=1){ if (tid<s) red[tid]=fmaxf(red[tid],red[tid+s]); __syncthreads(); }
  m = red[0]; __syncthreads();
  float ssum = 0.f;
  for (int j = tid; j < N; j += 128){ float e = expf(z[j]-m); z[j]=e; ssum += e; }
  red[tid] = ssum; __syncthreads();
  for (int s=64;s>0;s>>=1){ if (tid<s) red[tid]+=red[tid+s]; __syncthreads(); }
  float inv = 1.f/red[0]; __syncthreads();
  const float* wh = f + OWH + (size_t)h*N*OUTD;
  float acc = 0.f;
  for (int j=0;j<N;j++){
    float w = z[j];
    if (w != 0.f) acc += w * wh[(size_t)j*OUTD + tid];
  }
  f[OH1 + (size_t)n*CAT + h*OUTD + tid] = eluf(acc*inv);
}

// ---------------- pool1 node dots ----------------
__global__ void k_xw1(Params P){
  int n = blockIdx.x, wch = blockIdx.y, g = blockIdx.z, tid = threadIdx.x;
  __shared__ float sb[256];
  float* f = gf(g);
  const float* x = f + OH1 + (size_t)n*CAT;
  const float* w = P.ep1_w + wch*CAT;
  float acc = 0.f;
  for (int c = tid; c < CAT; c += 256) acc += x[c]*w[c];
  sb[tid] = acc; __syncthreads();
  for (int s=128;s>0;s>>=1){ if (tid<s) sb[tid]+=sb[tid+s]; __syncthreads(); }
  if (tid==0) f[(wch? OXW2:OXW1) + n] = sb[0];
}

// ---------------- pool1 edge scores + segment sums ----------------
__global__ void k_s1(Params P){
  int e = blockIdx.x*256 + threadIdx.x, g = blockIdx.y;
  if (e >= E) return;
  float* f = gf(g);
  const int* ei = P.g[g].eidx;
  int s = ei[e], d = ei[E+e];
  float v = sigmf(f[OXW1+s] + f[OXW2+d] + f[OEW1+e] + P.ep1_b[0]);
  f[OS1+e] = v;
  atomicAdd(&f[OSS1+s], v);
  atomicAdd(&f[ODEG1+s], 1.f);
}

__global__ void k_ns(int odeg, int oss, int ons){
  int g = blockIdx.y, n = threadIdx.x;
  if (n < N){ float* f = gf(g); f[ons+n] = f[oss+n]/(f[odeg+n]+1e-6f); }
}

// ---------------- pairIdx: last edge wins ----------------
__global__ void k_pairs(Params P){
  int e = blockIdx.x*256 + threadIdx.x, g = blockIdx.y;
  if (e >= E) return;
  const int* ei = P.g[g].eidx;
  atomicMax(&gpidx(g)[ei[e]*N + ei[E+e]], e);
}

// ---------------- global attention pool ----------------
__global__ void k_gpool_gate(Params P, int xoff, int D, int scaleoff, const float* w, const float* b){
  int n = blockIdx.x, g = blockIdx.y, tid = threadIdx.x;
  __shared__ float sb[256];
  float* f = gf(g);
  const float* x = f + xoff + (size_t)n*D;
  float acc = 0.f;
  for (int c = tid; c < D; c += 256) acc += x[c]*w[c];
  sb[tid] = acc; __syncthreads();
  for (int s=128;s>0;s>>=1){ if (tid<s) sb[tid]+=sb[tid+s]; __syncthreads(); }
  if (tid==0){
    float sc = scaleoff>=0 ? f[scaleoff+n] : 1.f;
    f[OGATE+n] = sigmf(sb[0]*sc + b[0]);
  }
}

__global__ void k_gpool_out(Params P, int xoff, int D, int scaleoff, int outoff){
  int g = blockIdx.x, tid = threadIdx.x;
  __shared__ float att[N];
  __shared__ float sb[256];
  float* f = gf(g);
  float m = -3e38f;
  for (int n = tid; n < N; n += 256) m = fmaxf(m, f[OGATE+n]);
  sb[tid] = m; __syncthreads();
  for (int s=128;s>0;s>>=1){ if (tid<s) sb[tid]=fmaxf(sb[tid],sb[tid+s]); __syncthreads(); }
  m = sb[0]; __syncthreads();
  float ss = 0.f;
  for (int n = tid; n < N; n += 256){ float e = expf(f[OGATE+n]-m); att[n]=e; ss += e; }
  sb[tid] = ss; __syncthreads();
  for (int s=128;s>0;s>>=1){ if (tid<s) sb[tid]+=sb[tid+s]; __syncthreads(); }
  float inv = 1.f/sb[0]; __syncthreads();
  for (int n = tid; n < N; n += 256){
    float sc = scaleoff>=0 ? f[scaleoff+n] : 1.f;
    att[n] *= inv*sc;
  }
  __syncthreads();
  const float* x = f + xoff;
  for (int c = tid; c < D; c += 256){
    float acc = 0.f;
    for (int n=0;n<N;n++) acc += att[n]*x[(size_t)n*D + c];
    gxseq()[g*SEQD + outoff + c] = acc;
  }
}

// ---------------- Wh2 = (h1cat @ W_out) * ns1 ----------------
__global__ void k_Wh2(Params P){
  int n = blockIdx.x, g = blockIdx.y, tid = threadIdx.x;
  __shared__ float hrow[128];
  float* f = gf(g);
  const float* x = f + OH1 + (size_t)n*CAT;
  float ns = f[ONS1+n];
  float acc = 0.f;
  for (int c0=0;c0<CAT;c0+=128){
    __syncthreads();
    hrow[tid] = x[c0+tid];
    __syncthreads();
    const float* W = P.W_out + (size_t)c0*OUTD + tid;
    for (int cc=0;cc<128;cc++) acc += hrow[cc]*W[(size_t)cc*OUTD];
  }
  f[OWH2 + (size_t)n*OUTD + tid] = acc*ns;
}

__global__ void k_asad2(Params P){
  int g = blockIdx.x;
  float* f = gf(g);
  for (int n = threadIdx.x; n < N; n += 256){
    const float* wh = f + OWH2 + (size_t)n*OUTD;
    float s=0.f, d=0.f;
    for (int o=0;o<OUTD;o++){
      float v = wh[o];
      s += v*P.ao_src[o];
      d += v*P.ao_dst[o];
    }
    f[OAS2+n]=s; f[OAD2+n]=d;
  }
}

// ---------------- GAT layer 2 ----------------
__global__ void k_att2(Params P){
  int n = blockIdx.x, g = blockIdx.y, tid = threadIdx.x;
  __shared__ float z[N];
  __shared__ float red[128];
  float* f = gf(g);
  const float* adj = P.g[g].adj;
  const int* pidx = gpidx(g);
  float asn = f[OAS2+n];
  const float* adn = f + OAD2;
  for (int j = tid; j < N; j += 128){
    float a = adj[n*N + j];
    float zz;
    if (a > 0.f){
      int p = pidx[n*N + j];
      float ee = (p >= 0) ? f[OEWV+p]*f[OS1+p] : 0.f;
      zz = lreluf(asn + adn[j] + ee);
    } else zz = -1e9f;
    z[j] = zz;
  }
  __syncthreads();
  float m = -3e38f;
  for (int j = tid; j < N; j += 128) m = fmaxf(m, z[j]);
  red[tid] = m; __syncthreads();
  for (int s=64;s>0;s>>=1){ if (tid<s) red[tid]=fmaxf(red[tid],red[tid+s]); __syncthreads(); }
  m = red[0]; __syncthreads();
  float ssum = 0.f;
  for (int j = tid; j < N; j += 128){ float e = expf(z[j]-m); z[j]=e; ssum += e; }
  red[tid] = ssum; __syncthreads();
  for (int s=64;s>0;s>>=1){ if (tid<s) red[tid]+=red[tid+s]; __syncthreads(); }
  float inv = 1.f/red[0]; __syncthreads();
  const float* wh = f + OWH2;
  float acc = 0.f;
  for (int j=0;j<N;j++){
    float w = z[j];
    if (w != 0.f) acc += w * wh[(size_t)j*OUTD + tid];
  }
  f[OH2B + (size_t)n*OUTD + tid] = acc*inv;
}

// ---- e2 partial: register-tiled 4x4, fused ew1/ewv dots; replaces k_edot1 too ----
constexpr int TE2 = 16;
__global__ __launch_bounds__(128, 2) void k_e2p(Params P){
  int e0 = blockIdx.x*TE2, h = blockIdx.y, g = blockIdx.z, tid = threadIdx.x; // 128 thr
  int cg = tid & 31, eg = tid >> 5;    // 32 col-groups x 4 edge-groups
  int c4 = cg*4, e4 = eg*4;
  __shared__ float es_t[HID][TE2];     // [c][e] 4KB
  __shared__ float tcol_t[OUTD][TE2];  // [o][swizzled e] 8KB
  const float* __restrict__ ea = P.g[g].eattr + (size_t)e0*HID;
  for (int i = tid; i < TE2*HID; i += 128) es_t[i & 63][i >> 6] = ea[i];
  __syncthreads();
  // loop1: t[edge][col] = es . We_gat[h]
  const float* __restrict__ W1 = P.We_gat + (size_t)h*HID*OUTD;
  float t[4][4];
  #pragma unroll
  for (int i=0;i<4;i++){ t[i][0]=0.f; t[i][1]=0.f; t[i][2]=0.f; t[i][3]=0.f; }
  for (int c=0;c<HID;c++){
    float4 ev = *(const float4*)&es_t[c][e4];
    float4 w  = *(const float4*)&W1[(size_t)c*OUTD + c4];
    t[0][0]+=ev.x*w.x; t[0][1]+=ev.x*w.y; t[0][2]+=ev.x*w.z; t[0][3]+=ev.x*w.w;
    t[1][0]+=ev.y*w.x; t[1][1]+=ev.y*w.y; t[1][2]+=ev.y*w.z; t[1][3]+=ev.y*w.w;
    t[2][0]+=ev.z*w.x; t[2][1]+=ev.z*w.y; t[2][2]+=ev.z*w.z; t[2][3]+=ev.z*w.w;
    t[3][0]+=ev.w*w.x; t[3][1]+=ev.w*w.y; t[3][2]+=ev.w*w.z; t[3][3]+=ev.w*w.w;
  }
  #pragma unroll
  for (int i=0;i<4;i++){
    t[i][0]=eluf(t[i][0]); t[i][1]=eluf(t[i][1]); t[i][2]=eluf(t[i][2]); t[i][3]=eluf(t[i][3]);
  }
  // fused ew1/ewv partial dots from registers (replaces k_edot1)
  {
    float4 w1 = *(const float4*)&P.ep1_w[2*CAT + h*OUTD + c4];
    float4 wv = *(const float4*)&gv_e()[h*OUTD + c4];
    #pragma unroll
    for (int i=0;i<4;i++){
      float a1 = t[i][0]*w1.x + t[i][1]*w1.y + t[i][2]*w1.z + t[i][3]*w1.w;
      float a2 = t[i][0]*wv.x + t[i][1]*wv.y + t[i][2]*wv.z + t[i][3]*wv.w;
      for (int off=16;off>0;off>>=1){
        a1 += __shfl_down(a1,off,32);
        a2 += __shfl_down(a2,off,32);
      }
      if (cg==0){
        atomicAdd(&gf(g)[OEW1 + e0+e4+i], a1);
        atomicAdd(&gf(g)[OEWV + e0+e4+i], a2);
      }
    }
  }
  // store transposed+swizzled: row o=c4+j, edge-group eg at slot (eg + (o>>2))&3
  #pragma unroll
  for (int j=0;j<4;j++){
    int o = c4 + j;
    int slot = (eg + (o>>2)) & 3;
    float4 v; v.x=t[0][j]; v.y=t[1][j]; v.z=t[2][j]; v.w=t[3][j];
    *(float4*)&tcol_t[o][4*slot] = v;
  }
  __syncthreads();
  // loop2: acc[edge][col] = tcol . We_out[h-chunk]
  const float* __restrict__ W2 = P.We_out + (size_t)h*OUTD*OUTD;
  float acc[4][4];
  #pragma unroll
  for (int i=0;i<4;i++){ acc[i][0]=0.f; acc[i][1]=0.f; acc[i][2]=0.f; acc[i][3]=0.f; }
  for (int o=0;o<OUTD;o++){
    int slot = (eg + (o>>2)) & 3;
    float4 tv = *(const float4*)&tcol_t[o][4*slot];
    float4 w  = *(const float4*)&W2[(size_t)o*OUTD + c4];
    acc[0][0]+=tv.x*w.x; acc[0][1]+=tv.x*w.y; acc[0][2]+=tv.x*w.z; acc[0][3]+=tv.x*w.w;
    acc[1][0]+=tv.y*w.x; acc[1][1]+=tv.y*w.y; acc[1][2]+=tv.y*w.z; acc[1][3]+=tv.y*w.w;
    acc[2][0]+=tv.z*w.x; acc[2][1]+=tv.z*w.y; acc[2][2]+=tv.z*w.z; acc[2][3]+=tv.z*w.w;
    acc[3][0]+=tv.w*w.x; acc[3][1]+=tv.w*w.y; acc[3][2]+=tv.w*w.z; acc[3][3]+=tv.w*w.w;
  }
  float* dst = G_E2PART + (((size_t)h*2 + g)*E + e0)*OUTD;
  #pragma unroll
  for (int i=0;i<4;i++){
    float4 v; v.x=acc[i][0]; v.y=acc[i][1]; v.z=acc[i][2]; v.w=acc[i][3];
    *(float4*)&dst[(size_t)(e4+i)*OUTD + c4] = v;
  }
}

// ---- finish: sum 16 head-partials, elu, dot ep2_w ----
__global__ void k_ew2fin(Params P){
  int e0 = blockIdx.x*TE2, g = blockIdx.y, tid = threadIdx.x;  // 128 thr
  __shared__ float lred[2][TE2];
  float* f = gf(g);
  float w2 = P.ep2_w[2*OUTD + tid];
  int lane = tid & 63, wvi = tid >> 6;
  for (int e=0;e<TE2;e++){
    const float* src = G_E2PART + ((size_t)g*E + e0 + e)*OUTD + tid;
    float a = 0.f;
    for (int h=0;h<NH;h++) a += src[(size_t)h*2*E*OUTD];
    float v = eluf(f[OS1+e0+e]*a) * w2;
    for (int off=32;off>0;off>>=1) v += __shfl_down(v,off);
    if (lane==0) lred[wvi][e]=v;
  }
  __syncthreads();
  if (tid < TE2) f[OEW2+e0+tid] = lred[0][tid]+lred[1][tid];
}

// ---------------- pool2 node dots ----------------
__global__ void k_xsd2(Params P){
  int g = blockIdx.x;
  float* f = gf(g);
  for (int n = threadIdx.x; n < N; n += 256){
    const float* x = f + OH2B + (size_t)n*OUTD;
    float s=0.f, d=0.f;
    for (int k=0;k<OUTD;k++){
      float v = x[k];
      s += v*P.ep2_w[k];
      d += v*P.ep2_w[OUTD+k];
    }
    f[OXS2+n]=s; f[OXD2+n]=d;
  }
}

__global__ void k_s2(Params P){
  int e = blockIdx.x*256 + threadIdx.x, g = blockIdx.y;
  if (e >= E) return;
  float* f = gf(g);
  const int* ei = P.g[g].eidx;
  int s = ei[e], d = ei[E+e];
  float v = sigmf(f[OXS2+s] + f[OXD2+d] + f[OEW2+e] + P.ep2_b[0]);
  f[OS2+e] = v;
  atomicAdd(&f[OSS2+s], v);
  atomicAdd(&f[ODEG2+s], 1.f);
}

// ---- LSTM input projection ----
__global__ void k_lstm_xg(Params P, int layer){
  int gid = blockIdx.x*4 + (threadIdx.x>>6);
  int lane = threadIdx.x & 63;
  int t = gid >> 10;
  int rem = gid & 1023;
  int d = rem >> 9;
  int gate = rem & 511;
  const float* Wih = layer ? P.Wih1 : P.Wih0;
  const float* bb  = layer ? P.b1   : P.b0;
  const float* xin = layer ? gy0()  : gxseq();
  int Din = layer ? 256 : SEQD;
  const float* x = xin + t*Din;
  const float* Wr = Wih + ((size_t)d*512 + gate)*Din;
  float acc = 0.f;
  for (int k=lane; k<Din; k+=64) acc += x[k]*Wr[k];
  for (int off=32; off>0; off>>=1) acc += __shfl_down(acc, off);
  if (lane==0) gxg()[(t*2 + d)*512 + gate] = acc + bb[d*512 + gate];
}

// ---- LSTM recurrence only ----
__global__ void k_lstm_rec(Params P, int layer){
  int d = blockIdx.x, tid = threadIdx.x;
  const float* Whh = layer ? P.Whh1 : P.Whh0;
  float* yout = layer ? gy1() : gy0();
  __shared__ float h[128], c[128], gbuf[512];
  if (tid < 128){ h[tid]=0.f; c[tid]=0.f; }
  __syncthreads();
  for (int s=0;s<2;s++){
    int t = (d==0) ? s : 1-s;
    float acc = gxg()[(t*2 + d)*512 + tid];
    const float* Ur = Whh + ((size_t)d*512 + tid)*128;
    for (int k=0;k<128;k++) acc += h[k]*Ur[k];
    gbuf[tid] = acc;
    __syncthreads();
    if (tid < 128){
      float ii = sigmf(gbuf[tid]);
      float ff = sigmf(gbuf[128+tid]);
      float gg = tanhf(gbuf[256+tid]);
      float oo = sigmf(gbuf[384+tid]);
      float cn = ff*c[tid] + ii*gg;
      c[tid] = cn;
      float hn = oo*tanhf(cn);
      h[tid] = hn;
      yout[t*256 + d*128 + tid] = hn;
    }
    __syncthreads();
  }
}

// ---------------- final FC + softmax ----------------
__global__ void k_final(Params P){
  int tid = threadIdx.x;
  __shared__ float sb[256], sb2[256];
  const float* x = gy1() + 256;
  sb[tid]  = x[tid]*P.fc_w[tid*2+0];
  sb2[tid] = x[tid]*P.fc_w[tid*2+1];
  __syncthreads();
  for (int s=128;s>0;s>>=1){ if (tid<s){ sb[tid]+=sb[tid+s]; sb2[tid]+=sb2[tid+s]; } __syncthreads(); }
  if (tid==0){
    float l0 = sb[0] + P.fc_b[0];
    float l1 = sb2[0] + P.fc_b[1];
    float m = fmaxf(l0,l1);
    float e0 = expf(l0-m), e1 = expf(l1-m), inv = 1.f/(e0+e1);
    P.out[0] = e0*inv;
    P.out[1] = e1*inv;
  }
}

extern "C" void kernel_launch(void* const* d_in, const int* in_sizes, int n_in,
                              void* d_out, int out_size, void* d_ws, size_t ws_size,
                              hipStream_t stream){
  Params P;
  for (int g=0; g<2; ++g){
    int b = g*5;
    P.g[g].feat  = (const float*)d_in[b+0];
    P.g[g].eidx  = (const int*)d_in[b+1];
    P.g[g].eattr = (const float*)d_in[b+2];
    P.g[g].adj   = (const float*)d_in[b+3];
    P.g[g].n2n   = (const float*)d_in[b+4];
  }
  P.W_h   = (const float*)d_in[10];
  P.W_gat = (const float*)d_in[11];
  P.a_src = (const float*)d_in[12];
  P.a_dst = (const float*)d_in[13];
  P.a_e   = (const float*)d_in[14];
  P.We_gat= (const float*)d_in[15];
  P.W_out = (const float*)d_in[16];
  P.ao_src= (const float*)d_in[17];
  P.ao_dst= (const float*)d_in[18];
  P.ao_e  = (const float*)d_in[19];
  P.We_out= (const float*)d_in[20];
  P.ep1_w = (const float*)d_in[21];
  P.ep1_b = (const float*)d_in[22];
  P.ep2_w = (const float*)d_in[23];
  P.ep2_b = (const float*)d_in[24];
  P.g1_w  = (const float*)d_in[25];
  P.g1_b  = (const float*)d_in[26];
  P.g2_w  = (const float*)d_in[27];
  P.g2_b  = (const float*)d_in[28];
  P.g3_w  = (const float*)d_in[29];
  P.g3_b  = (const float*)d_in[30];
  P.Wih0  = (const float*)d_in[31];
  P.Whh0  = (const float*)d_in[32];
  P.b0    = (const float*)d_in[33];
  P.Wih1  = (const float*)d_in[34];
  P.Whh1  = (const float*)d_in[35];
  P.b1    = (const float*)d_in[36];
  P.fc_w  = (const float*)d_in[37];
  P.fc_b  = (const float*)d_in[38];
  P.out   = (float*)d_out;

  // ---- graph stages ----
  k_zero <<<dim3((TOTF+255)/256 + 1), 256, 0, stream>>>();
  k_pre  <<<dim3((NH*HID+CAT+255)/256), 256, 0, stream>>>(P);
  k_e2p  <<<dim3(E/TE2,NH,2),128, 0, stream>>>(P);   // e2 partials + ew1/ewv (fused)
  k_pairs<<<dim3((E+255)/256,2), 256, 0, stream>>>(P);
  k_edoth<<<dim3(NH,2),   256, 0, stream>>>(P);
  k_h0   <<<dim3((2*N*HID+255)/256), 256, 0, stream>>>(P);
  k_gpool_gate<<<dim3(N,2), 256, 0, stream>>>(P, OH0, HID, -1, P.g1_w, P.g1_b);
  k_gpool_out <<<dim3(2),   256, 0, stream>>>(P, OH0, HID, -1, 0);
  k_Wh   <<<dim3(N,NH,2), 128, 0, stream>>>(P);
  k_asad <<<dim3(NH,2),   256, 0, stream>>>(P);
  k_att1 <<<dim3(N,NH,2), 128, 0, stream>>>(P);
  k_xw1  <<<dim3(N,2,2),  256, 0, stream>>>(P);
  k_s1   <<<dim3((E+255)/256,2), 256, 0, stream>>>(P);
  k_ns   <<<dim3(1,2),    256, 0, stream>>>(ODEG1, OSS1, ONS1);
  k_gpool_gate<<<dim3(N,2), 256, 0, stream>>>(P, OH1, CAT, ONS1, P.g2_w, P.g2_b);
  k_gpool_out <<<dim3(2),   256, 0, stream>>>(P, OH1, CAT, ONS1, HID);
  k_Wh2  <<<dim3(N,2),    128, 0, stream>>>(P);
  k_asad2<<<dim3(2),      256, 0, stream>>>(P);
  k_att2 <<<dim3(N,2),    128, 0, stream>>>(P);
  k_ew2fin<<<dim3(E/TE2,2),128, 0, stream>>>(P);
  k_xsd2 <<<dim3(2),      256, 0, stream>>>(P);
  k_s2   <<<dim3((E+255)/256,2), 256, 0, stream>>>(P);
  k_ns   <<<dim3(1,2),    256, 0, stream>>>(ODEG2, OSS2, ONS2);
  k_gpool_gate<<<dim3(N,2), 256, 0, stream>>>(P, OH2B, OUTD, ONS2, P.g3_w, P.g3_b);
  k_gpool_out <<<dim3(2),   256, 0, stream>>>(P, OH2B, OUTD, ONS2, HID+CAT);

  // ---- LSTM stack + classifier ----
  k_lstm_xg <<<dim3(512), 256, 0, stream>>>(P, 0);
  k_lstm_rec<<<dim3(2),   512, 0, stream>>>(P, 0);
  k_lstm_xg <<<dim3(512), 256, 0, stream>>>(P, 1);
  k_lstm_rec<<<dim3(2),   512, 0, stream>>>(P, 1);
  k_final<<<dim3(1), 256, 0, stream>>>(P);
}

// Round 12
// 496.682 us; speedup vs baseline: 3.6585x; 1.2758x over previous
//
#include <hip/hip_runtime.h>
#include <math.h>

#define DI static __device__ __forceinline__

DI float eluf(float x){ return x > 0.f ? x : expm1f(x); }
DI float lreluf(float x){ return x > 0.f ? x : 0.2f*x; }
DI float sigmf(float x){ return 1.f/(1.f+expf(-x)); }

constexpr int N=200, E=3200, HID=64, NH=16, OUTD=128, CAT=2048, SEQD=2240;

// ---- per-graph f32 scratch offsets (in floats) ----
constexpr int OH0   = 0;
constexpr int OWH   = OH0 + N*HID;
constexpr int OASN  = OWH + NH*N*OUTD;
constexpr int OADN  = OASN + NH*N;
constexpr int OH1   = OADN + NH*N;
constexpr int OXW1  = OH1 + N*CAT;
constexpr int OXW2  = OXW1 + 256;
constexpr int OEW1  = OXW2 + 256;
constexpr int OS1   = OEW1 + E;
constexpr int ODEG1 = OS1 + E;
constexpr int OSS1  = ODEG1 + 256;
constexpr int ONS1  = OSS1 + 256;
constexpr int OWH2  = ONS1 + 256;
constexpr int OAS2  = OWH2 + N*OUTD;
constexpr int OAD2  = OAS2 + 256;
constexpr int OEWV  = OAD2 + 256;
constexpr int OH2B  = OEWV + E;
constexpr int OXS2  = OH2B + N*OUTD;
constexpr int OXD2  = OXS2 + 256;
constexpr int OEW2  = OXD2 + 256;
constexpr int OS2   = OEW2 + E;
constexpr int ODEG2 = OS2 + E;
constexpr int OSS2  = ODEG2 + 256;
constexpr int ONS2  = OSS2 + 256;
constexpr int OGATE = ONS2 + 256;
constexpr int PGF   = OGATE + 256;
constexpr int GLOBF = 10624;
constexpr int TOTF  = GLOBF + 2*PGF;

// ---- static device scratch: independent of ws_size ----
__device__ float G_F[TOTF];
__device__ float G_E2PART[(size_t)NH*2*E*OUTD];   // per-head e2 partials (52 MB, no zero needed)
__device__ float G_EDOTH[2*NH*E];                  // eattr@weae per (g,h,e)
__device__ int   G_PIDX[2*N*N];

DI float* gf(int g){ return G_F + GLOBF + (size_t)g*PGF; }
DI float* gwe_ae(){ return G_F; }
DI float* gv_e(){ return G_F + 1024; }
DI float* gy0(){ return G_F + 3072; }
DI float* gy1(){ return G_F + 3584; }
DI float* gxseq(){ return G_F + 4096; }
DI float* gxg(){ return G_F + 8576; }
DI int*   gpidx(int g){ return G_PIDX + g*N*N; }

struct GraphIn {
  const float *feat, *eattr, *adj, *n2n;
  const int   *eidx;
};

struct Params {
  GraphIn g[2];
  const float *W_h, *W_gat, *a_src, *a_dst, *a_e, *We_gat;
  const float *W_out, *ao_src, *ao_dst, *ao_e, *We_out;
  const float *ep1_w, *ep1_b, *ep2_w, *ep2_b;
  const float *g1_w, *g1_b, *g2_w, *g2_b, *g3_w, *g3_b;
  const float *Wih0, *Whh0, *b0, *Wih1, *Whh1, *b1, *fc_w, *fc_b;
  float *out;
};

// ---------------- zero scratch; pairIdx=-1 ----------------
__global__ void k_zero(){
  int idx = blockIdx.x*256 + threadIdx.x;
  if (idx < TOTF) G_F[idx] = 0.f;
  if (idx < 2*N*N) G_PIDX[idx] = -1;
}

// ---------------- precontract We@a_e vectors ----------------
__global__ void k_pre(Params P){
  int idx = blockIdx.x*256 + threadIdx.x;
  if (idx < NH*HID){
    int h = idx/HID, c = idx%HID;
    const float* W = P.We_gat + (size_t)(h*HID + c)*OUTD;
    const float* a = P.a_e + h*OUTD;
    float acc = 0.f;
    for (int o=0;o<OUTD;o++) acc += W[o]*a[o];
    gwe_ae()[idx] = acc;
  } else if (idx < NH*HID + CAT){
    int c = idx - NH*HID;
    const float* W = P.We_out + (size_t)c*OUTD;
    float acc = 0.f;
    for (int o=0;o<OUTD;o++) acc += W[o]*P.ao_e[o];
    gv_e()[c] = acc;
  }
}

// ---------------- h0 = elu(feat @ W_h) ----------------
__global__ void k_h0(Params P){
  int idx = blockIdx.x*256 + threadIdx.x;
  if (idx >= 2*N*HID) return;
  int g = idx/(N*HID), r = idx%(N*HID), n = r/HID, c = r%HID;
  const float* feat = P.g[g].feat;
  float acc = 0.f;
  for (int k=0;k<HID;k++) acc += feat[n*HID+k]*P.W_h[k*HID+c];
  gf(g)[OH0 + n*HID + c] = eluf(acc);
}

// ---------------- Wh[h] = h0 @ W_gat[h] ----------------
__global__ void k_Wh(Params P){
  int n = blockIdx.x, h = blockIdx.y, g = blockIdx.z, o = threadIdx.x;
  __shared__ float hs[HID];
  float* f = gf(g);
  if (o < HID) hs[o] = f[OH0 + n*HID + o];
  __syncthreads();
  const float* W = P.W_gat + (size_t)h*HID*OUTD + o;
  float acc = 0.f;
  for (int c=0;c<HID;c++) acc += hs[c]*W[(size_t)c*OUTD];
  f[OWH + ((size_t)h*N + n)*OUTD + o] = acc;
}

// ---------------- asn/adn = Wh @ a_src / a_dst ----------------
__global__ void k_asad(Params P){
  int h = blockIdx.x, g = blockIdx.y;
  float* f = gf(g);
  for (int n = threadIdx.x; n < N; n += 256){
    const float* wh = f + OWH + ((size_t)h*N + n)*OUTD;
    float s=0.f, d=0.f;
    for (int o=0;o<OUTD;o++){
      float v = wh[o];
      s += v*P.a_src[h*OUTD+o];
      d += v*P.a_dst[h*OUTD+o];
    }
    f[OASN + h*N + n] = s;
    f[OADN + h*N + n] = d;
  }
}

// ---------------- GAT layer 1: edge term via EDOTH lookup ----------------
__global__ void k_att1(Params P){
  int n = blockIdx.x, h = blockIdx.y, g = blockIdx.z, tid = threadIdx.x;
  __shared__ float z[N];
  __shared__ float red[128];
  float* f = gf(g);
  const float* adj = P.g[g].adj;
  const int* pidx = gpidx(g);
  const float* edoth = G_EDOTH + ((size_t)g*NH + h)*E;
  float asn = f[OASN + h*N + n];
  const float* adn = f + OADN + h*N;
  for (int j = tid; j < N; j += 128){
    float a = adj[n*N + j];
    float zz;
    if (a > 0.f){
      int p = pidx[n*N + j];
      float ee = (p >= 0) ? edoth[p] : 0.f;
      zz = lreluf(asn + adn[j] + ee);
    } else zz = -1e9f;
    z[j] = zz;
  }
  __syncthreads();
  float m = -3e38f;
  for (int j = tid; j < N; j += 128) m = fmaxf(m, z[j]);
  red[tid] = m; __syncthreads();
  for (int s=64;s>0;s>>=1){ if (tid<s) red[tid]=fmaxf(red[tid],red[tid+s]); __syncthreads(); }
  m = red[0]; __syncthreads();
  float ssum = 0.f;
  for (int j = tid; j < N; j += 128){ float e = expf(z[j]-m); z[j]=e; ssum += e; }
  red[tid] = ssum; __syncthreads();
  for (int s=64;s>0;s>>=1){ if (tid<s) red[tid]+=red[tid+s]; __syncthreads(); }
  float inv = 1.f/red[0]; __syncthreads();
  const float* wh = f + OWH + (size_t)h*N*OUTD;
  float acc = 0.f;
  for (int j=0;j<N;j++){
    float w = z[j];
    if (w != 0.f) acc += w * wh[(size_t)j*OUTD + tid];
  }
  f[OH1 + (size_t)n*CAT + h*OUTD + tid] = eluf(acc*inv);
}

// ---------------- pool1 node dots ----------------
__global__ void k_xw1(Params P){
  int n = blockIdx.x, wch = blockIdx.y, g = blockIdx.z, tid = threadIdx.x;
  __shared__ float sb[256];
  float* f = gf(g);
  const float* x = f + OH1 + (size_t)n*CAT;
  const float* w = P.ep1_w + wch*CAT;
  float acc = 0.f;
  for (int c = tid; c < CAT; c += 256) acc += x[c]*w[c];
  sb[tid] = acc; __syncthreads();
  for (int s=128;s>0;s>>=1){ if (tid<s) sb[tid]+=sb[tid+s]; __syncthreads(); }
  if (tid==0) f[(wch? OXW2:OXW1) + n] = sb[0];
}

// ---------------- pool1 edge scores + segment sums ----------------
__global__ void k_s1(Params P){
  int e = blockIdx.x*256 + threadIdx.x, g = blockIdx.y;
  if (e >= E) return;
  float* f = gf(g);
  const int* ei = P.g[g].eidx;
  int s = ei[e], d = ei[E+e];
  float v = sigmf(f[OXW1+s] + f[OXW2+d] + f[OEW1+e] + P.ep1_b[0]);
  f[OS1+e] = v;
  atomicAdd(&f[OSS1+s], v);
  atomicAdd(&f[ODEG1+s], 1.f);
}

__global__ void k_ns(int odeg, int oss, int ons){
  int g = blockIdx.y, n = threadIdx.x;
  if (n < N){ float* f = gf(g); f[ons+n] = f[oss+n]/(f[odeg+n]+1e-6f); }
}

// ---------------- pairIdx: last edge wins ----------------
__global__ void k_pairs(Params P){
  int e = blockIdx.x*256 + threadIdx.x, g = blockIdx.y;
  if (e >= E) return;
  const int* ei = P.g[g].eidx;
  atomicMax(&gpidx(g)[ei[e]*N + ei[E+e]], e);
}

// ---------------- global attention pool (gate) ----------------
__global__ void k_gpool_gate(Params P, int xoff, int D, int scaleoff, const float* w, const float* b){
  int n = blockIdx.x, g = blockIdx.y, tid = threadIdx.x;
  __shared__ float sb[256];
  float* f = gf(g);
  const float* x = f + xoff + (size_t)n*D;
  float acc = 0.f;
  for (int c = tid; c < D; c += 256) acc += x[c]*w[c];
  sb[tid] = acc; __syncthreads();
  for (int s=128;s>0;s>>=1){ if (tid<s) sb[tid]+=sb[tid+s]; __syncthreads(); }
  if (tid==0){
    float sc = scaleoff>=0 ? f[scaleoff+n] : 1.f;
    f[OGATE+n] = sigmf(sb[0]*sc + b[0]);
  }
}

// ---- gpool output: column-tiled across grid.x for occupancy ----
__global__ void k_gpool_out(Params P, int xoff, int D, int scaleoff, int outoff){
  int cb = blockIdx.x, g = blockIdx.y, tid = threadIdx.x;
  __shared__ float att[N];
  __shared__ float sb[256];
  float* f = gf(g);
  float m = -3e38f;
  for (int n = tid; n < N; n += 256) m = fmaxf(m, f[OGATE+n]);
  sb[tid] = m; __syncthreads();
  for (int s=128;s>0;s>>=1){ if (tid<s) sb[tid]=fmaxf(sb[tid],sb[tid+s]); __syncthreads(); }
  m = sb[0]; __syncthreads();
  float ss = 0.f;
  for (int n = tid; n < N; n += 256){ float e = expf(f[OGATE+n]-m); att[n]=e; ss += e; }
  sb[tid] = ss; __syncthreads();
  for (int s=128;s>0;s>>=1){ if (tid<s) sb[tid]+=sb[tid+s]; __syncthreads(); }
  float inv = 1.f/sb[0]; __syncthreads();
  for (int n = tid; n < N; n += 256){
    float sc = scaleoff>=0 ? f[scaleoff+n] : 1.f;
    att[n] *= inv*sc;
  }
  __syncthreads();
  int c = cb*256 + tid;
  if (c < D){
    const float* x = f + xoff;
    float acc = 0.f;
    for (int n=0;n<N;n++) acc += att[n]*x[(size_t)n*D + c];
    gxseq()[g*SEQD + outoff + c] = acc;
  }
}

// ---- Wh2 = (h1cat @ W_out) * ns1 ; 512 thr, in-block K-split ----
__global__ void k_Wh2(Params P){
  int n = blockIdx.x, g = blockIdx.y, tid = threadIdx.x;   // 512 threads
  int kq = tid >> 7, o = tid & 127;                        // 4 K-quarters x 128 cols
  __shared__ float hrow[4][128];
  __shared__ float part[4][128];
  float* f = gf(g);
  const float* x = f + OH1 + (size_t)n*CAT;
  float acc = 0.f;
  for (int cc=0; cc<4; cc++){
    int c0 = kq*512 + cc*128;
    __syncthreads();
    hrow[kq][o] = x[c0 + o];
    __syncthreads();
    const float* W = P.W_out + (size_t)c0*OUTD + o;
    for (int j=0;j<128;j++) acc += hrow[kq][j]*W[(size_t)j*OUTD];
  }
  part[kq][o] = acc;
  __syncthreads();
  if (kq==0){
    float ns = f[ONS1+n];
    float a = part[0][o]+part[1][o]+part[2][o]+part[3][o];
    f[OWH2 + (size_t)n*OUTD + o] = a*ns;
  }
}

__global__ void k_asad2(Params P){
  int g = blockIdx.x;
  float* f = gf(g);
  for (int n = threadIdx.x; n < N; n += 256){
    const float* wh = f + OWH2 + (size_t)n*OUTD;
    float s=0.f, d=0.f;
    for (int o=0;o<OUTD;o++){
      float v = wh[o];
      s += v*P.ao_src[o];
      d += v*P.ao_dst[o];
    }
    f[OAS2+n]=s; f[OAD2+n]=d;
  }
}

// ---------------- GAT layer 2 ----------------
__global__ void k_att2(Params P){
  int n = blockIdx.x, g = blockIdx.y, tid = threadIdx.x;
  __shared__ float z[N];
  __shared__ float red[128];
  float* f = gf(g);
  const float* adj = P.g[g].adj;
  const int* pidx = gpidx(g);
  float asn = f[OAS2+n];
  const float* adn = f + OAD2;
  for (int j = tid; j < N; j += 128){
    float a = adj[n*N + j];
    float zz;
    if (a > 0.f){
      int p = pidx[n*N + j];
      float ee = (p >= 0) ? f[OEWV+p]*f[OS1+p] : 0.f;
      zz = lreluf(asn + adn[j] + ee);
    } else zz = -1e9f;
    z[j] = zz;
  }
  __syncthreads();
  float m = -3e38f;
  for (int j = tid; j < N; j += 128) m = fmaxf(m, z[j]);
  red[tid] = m; __syncthreads();
  for (int s=64;s>0;s>>=1){ if (tid<s) red[tid]=fmaxf(red[tid],red[tid+s]); __syncthreads(); }
  m = red[0]; __syncthreads();
  float ssum = 0.f;
  for (int j = tid; j < N; j += 128){ float e = expf(z[j]-m); z[j]=e; ssum += e; }
  red[tid] = ssum; __syncthreads();
  for (int s=64;s>0;s>>=1){ if (tid<s) red[tid]+=red[tid+s]; __syncthreads(); }
  float inv = 1.f/red[0]; __syncthreads();
  const float* wh = f + OWH2;
  float acc = 0.f;
  for (int j=0;j<N;j++){
    float w = z[j];
    if (w != 0.f) acc += w * wh[(size_t)j*OUTD + tid];
  }
  f[OH2B + (size_t)n*OUTD + tid] = acc*inv;
}

// ---- e2 partial: register-tiled 4x4, fused ew1/ewv + EDOTH; conflict-free staging ----
constexpr int TE2 = 16;
__global__ __launch_bounds__(128, 2) void k_e2p(Params P){
  int e0 = blockIdx.x*TE2, h = blockIdx.y, g = blockIdx.z, tid = threadIdx.x; // 128 thr
  int cg = tid & 31, eg = tid >> 5;    // 32 col-groups x 4 edge-groups
  int c4 = cg*4, e4 = eg*4;
  __shared__ float es_t[HID][TE2+1];   // stride-17 rows: staging is bank-conflict-free
  __shared__ float tcol_t[OUTD][TE2];  // [o][swizzled e]
  const float* __restrict__ ea = P.g[g].eattr + (size_t)e0*HID;
  for (int i = tid; i < TE2*HID; i += 128) es_t[i & 63][i >> 6] = ea[i];
  __syncthreads();
  // loop1: t[edge][col] = es . We_gat[h]; fused EDOTH dot (raw es . weae)
  const float* __restrict__ W1 = P.We_gat + (size_t)h*HID*OUTD;
  const float* __restrict__ weae = gwe_ae() + h*HID;
  float t[4][4];
  float ed[4] = {0.f,0.f,0.f,0.f};
  #pragma unroll
  for (int i=0;i<4;i++){ t[i][0]=0.f; t[i][1]=0.f; t[i][2]=0.f; t[i][3]=0.f; }
  for (int c=0;c<HID;c++){
    float ev0 = es_t[c][e4+0], ev1 = es_t[c][e4+1], ev2 = es_t[c][e4+2], ev3 = es_t[c][e4+3];
    float4 w  = *(const float4*)&W1[(size_t)c*OUTD + c4];
    t[0][0]+=ev0*w.x; t[0][1]+=ev0*w.y; t[0][2]+=ev0*w.z; t[0][3]+=ev0*w.w;
    t[1][0]+=ev1*w.x; t[1][1]+=ev1*w.y; t[1][2]+=ev1*w.z; t[1][3]+=ev1*w.w;
    t[2][0]+=ev2*w.x; t[2][1]+=ev2*w.y; t[2][2]+=ev2*w.z; t[2][3]+=ev2*w.w;
    t[3][0]+=ev3*w.x; t[3][1]+=ev3*w.y; t[3][2]+=ev3*w.z; t[3][3]+=ev3*w.w;
    float wc = weae[c];
    ed[0]+=ev0*wc; ed[1]+=ev1*wc; ed[2]+=ev2*wc; ed[3]+=ev3*wc;
  }
  if (cg==0){
    float* eo = G_EDOTH + ((size_t)g*NH+h)*E + e0 + e4;
    eo[0]=ed[0]; eo[1]=ed[1]; eo[2]=ed[2]; eo[3]=ed[3];
  }
  #pragma unroll
  for (int i=0;i<4;i++){
    t[i][0]=eluf(t[i][0]); t[i][1]=eluf(t[i][1]); t[i][2]=eluf(t[i][2]); t[i][3]=eluf(t[i][3]);
  }
  // fused ew1/ewv partial dots from registers
  {
    float4 w1 = *(const float4*)&P.ep1_w[2*CAT + h*OUTD + c4];
    float4 wv = *(const float4*)&gv_e()[h*OUTD + c4];
    #pragma unroll
    for (int i=0;i<4;i++){
      float a1 = t[i][0]*w1.x + t[i][1]*w1.y + t[i][2]*w1.z + t[i][3]*w1.w;
      float a2 = t[i][0]*wv.x + t[i][1]*wv.y + t[i][2]*wv.z + t[i][3]*wv.w;
      for (int off=16;off>0;off>>=1){
        a1 += __shfl_down(a1,off,32);
        a2 += __shfl_down(a2,off,32);
      }
      if (cg==0){
        atomicAdd(&gf(g)[OEW1 + e0+e4+i], a1);
        atomicAdd(&gf(g)[OEWV + e0+e4+i], a2);
      }
    }
  }
  // store transposed+swizzled: row o=c4+j, edge-group eg at slot (eg + (o>>2))&3
  #pragma unroll
  for (int j=0;j<4;j++){
    int o = c4 + j;
    int slot = (eg + (o>>2)) & 3;
    float4 v; v.x=t[0][j]; v.y=t[1][j]; v.z=t[2][j]; v.w=t[3][j];
    *(float4*)&tcol_t[o][4*slot] = v;
  }
  __syncthreads();
  // loop2: acc[edge][col] = tcol . We_out[h-chunk]
  const float* __restrict__ W2 = P.We_out + (size_t)h*OUTD*OUTD;
  float acc[4][4];
  #pragma unroll
  for (int i=0;i<4;i++){ acc[i][0]=0.f; acc[i][1]=0.f; acc[i][2]=0.f; acc[i][3]=0.f; }
  #pragma unroll 4
  for (int o=0;o<OUTD;o++){
    int slot = (eg + (o>>2)) & 3;
    float4 tv = *(const float4*)&tcol_t[o][4*slot];
    float4 w  = *(const float4*)&W2[(size_t)o*OUTD + c4];
    acc[0][0]+=tv.x*w.x; acc[0][1]+=tv.x*w.y; acc[0][2]+=tv.x*w.z; acc[0][3]+=tv.x*w.w;
    acc[1][0]+=tv.y*w.x; acc[1][1]+=tv.y*w.y; acc[1][2]+=tv.y*w.z; acc[1][3]+=tv.y*w.w;
    acc[2][0]+=tv.z*w.x; acc[2][1]+=tv.z*w.y; acc[2][2]+=tv.z*w.z; acc[2][3]+=tv.z*w.w;
    acc[3][0]+=tv.w*w.x; acc[3][1]+=tv.w*w.y; acc[3][2]+=tv.w*w.z; acc[3][3]+=tv.w*w.w;
  }
  float* dst = G_E2PART + (((size_t)h*2 + g)*E + e0)*OUTD;
  #pragma unroll
  for (int i=0;i<4;i++){
    float4 v; v.x=acc[i][0]; v.y=acc[i][1]; v.z=acc[i][2]; v.w=acc[i][3];
    *(float4*)&dst[(size_t)(e4+i)*OUTD + c4] = v;
  }
}

// ---- finish: sum 16 head-partials, elu, dot ep2_w ----
__global__ void k_ew2fin(Params P){
  int e0 = blockIdx.x*TE2, g = blockIdx.y, tid = threadIdx.x;  // 128 thr
  __shared__ float lred[2][TE2];
  float* f = gf(g);
  float w2 = P.ep2_w[2*OUTD + tid];
  int lane = tid & 63, wvi = tid >> 6;
  for (int e=0;e<TE2;e++){
    const float* src = G_E2PART + ((size_t)g*E + e0 + e)*OUTD + tid;
    float a = 0.f;
    for (int h=0;h<NH;h++) a += src[(size_t)h*2*E*OUTD];
    float v = eluf(f[OS1+e0+e]*a) * w2;
    for (int off=32;off>0;off>>=1) v += __shfl_down(v,off);
    if (lane==0) lred[wvi][e]=v;
  }
  __syncthreads();
  if (tid < TE2) f[OEW2+e0+tid] = lred[0][tid]+lred[1][tid];
}

// ---------------- pool2 node dots ----------------
__global__ void k_xsd2(Params P){
  int g = blockIdx.x;
  float* f = gf(g);
  for (int n = threadIdx.x; n < N; n += 256){
    const float* x = f + OH2B + (size_t)n*OUTD;
    float s=0.f, d=0.f;
    for (int k=0;k<OUTD;k++){
      float v = x[k];
      s += v*P.ep2_w[k];
      d += v*P.ep2_w[OUTD+k];
    }
    f[OXS2+n]=s; f[OXD2+n]=d;
  }
}

__global__ void k_s2(Params P){
  int e = blockIdx.x*256 + threadIdx.x, g = blockIdx.y;
  if (e >= E) return;
  float* f = gf(g);
  const int* ei = P.g[g].eidx;
  int s = ei[e], d = ei[E+e];
  float v = sigmf(f[OXS2+s] + f[OXD2+d] + f[OEW2+e] + P.ep2_b[0]);
  f[OS2+e] = v;
  atomicAdd(&f[OSS2+s], v);
  atomicAdd(&f[ODEG2+s], 1.f);
}

// ---- LSTM input projection ----
__global__ void k_lstm_xg(Params P, int layer){
  int gid = blockIdx.x*4 + (threadIdx.x>>6);
  int lane = threadIdx.x & 63;
  int t = gid >> 10;
  int rem = gid & 1023;
  int d = rem >> 9;
  int gate = rem & 511;
  const float* Wih = layer ? P.Wih1 : P.Wih0;
  const float* bb  = layer ? P.b1   : P.b0;
  const float* xin = layer ? gy0()  : gxseq();
  int Din = layer ? 256 : SEQD;
  const float* x = xin + t*Din;
  const float* Wr = Wih + ((size_t)d*512 + gate)*Din;
  float acc = 0.f;
  for (int k=lane; k<Din; k+=64) acc += x[k]*Wr[k];
  for (int off=32; off>0; off>>=1) acc += __shfl_down(acc, off);
  if (lane==0) gxg()[(t*2 + d)*512 + gate] = acc + bb[d*512 + gate];
}

// ---- LSTM recurrence only ----
__global__ void k_lstm_rec(Params P, int layer){
  int d = blockIdx.x, tid = threadIdx.x;
  const float* Whh = layer ? P.Whh1 : P.Whh0;
  float* yout = layer ? gy1() : gy0();
  __shared__ float h[128], c[128], gbuf[512];
  if (tid < 128){ h[tid]=0.f; c[tid]=0.f; }
  __syncthreads();
  for (int s=0;s<2;s++){
    int t = (d==0) ? s : 1-s;
    float acc = gxg()[(t*2 + d)*512 + tid];
    const float* Ur = Whh + ((size_t)d*512 + tid)*128;
    for (int k=0;k<128;k++) acc += h[k]*Ur[k];
    gbuf[tid] = acc;
    __syncthreads();
    if (tid < 128){
      float ii = sigmf(gbuf[tid]);
      float ff = sigmf(gbuf[128+tid]);
      float gg = tanhf(gbuf[256+tid]);
      float oo = sigmf(gbuf[384+tid]);
      float cn = ff*c[tid] + ii*gg;
      c[tid] = cn;
      float hn = oo*tanhf(cn);
      h[tid] = hn;
      yout[t*256 + d*128 + tid] = hn;
    }
    __syncthreads();
  }
}

// ---------------- final FC + softmax ----------------
__global__ void k_final(Params P){
  int tid = threadIdx.x;
  __shared__ float sb[256], sb2[256];
  const float* x = gy1() + 256;
  sb[tid]  = x[tid]*P.fc_w[tid*2+0];
  sb2[tid] = x[tid]*P.fc_w[tid*2+1];
  __syncthreads();
  for (int s=128;s>0;s>>=1){ if (tid<s){ sb[tid]+=sb[tid+s]; sb2[tid]+=sb2[tid+s]; } __syncthreads(); }
  if (tid==0){
    float l0 = sb[0] + P.fc_b[0];
    float l1 = sb2[0] + P.fc_b[1];
    float m = fmaxf(l0,l1);
    float e0 = expf(l0-m), e1 = expf(l1-m), inv = 1.f/(e0+e1);
    P.out[0] = e0*inv;
    P.out[1] = e1*inv;
  }
}

extern "C" void kernel_launch(void* const* d_in, const int* in_sizes, int n_in,
                              void* d_out, int out_size, void* d_ws, size_t ws_size,
                              hipStream_t stream){
  Params P;
  for (int g=0; g<2; ++g){
    int b = g*5;
    P.g[g].feat  = (const float*)d_in[b+0];
    P.g[g].eidx  = (const int*)d_in[b+1];
    P.g[g].eattr = (const float*)d_in[b+2];
    P.g[g].adj   = (const float*)d_in[b+3];
    P.g[g].n2n   = (const float*)d_in[b+4];
  }
  P.W_h   = (const float*)d_in[10];
  P.W_gat = (const float*)d_in[11];
  P.a_src = (const float*)d_in[12];
  P.a_dst = (const float*)d_in[13];
  P.a_e   = (const float*)d_in[14];
  P.We_gat= (const float*)d_in[15];
  P.W_out = (const float*)d_in[16];
  P.ao_src= (const float*)d_in[17];
  P.ao_dst= (const float*)d_in[18];
  P.ao_e  = (const float*)d_in[19];
  P.We_out= (const float*)d_in[20];
  P.ep1_w = (const float*)d_in[21];
  P.ep1_b = (const float*)d_in[22];
  P.ep2_w = (const float*)d_in[23];
  P.ep2_b = (const float*)d_in[24];
  P.g1_w  = (const float*)d_in[25];
  P.g1_b  = (const float*)d_in[26];
  P.g2_w  = (const float*)d_in[27];
  P.g2_b  = (const float*)d_in[28];
  P.g3_w  = (const float*)d_in[29];
  P.g3_b  = (const float*)d_in[30];
  P.Wih0  = (const float*)d_in[31];
  P.Whh0  = (const float*)d_in[32];
  P.b0    = (const float*)d_in[33];
  P.Wih1  = (const float*)d_in[34];
  P.Whh1  = (const float*)d_in[35];
  P.b1    = (const float*)d_in[36];
  P.fc_w  = (const float*)d_in[37];
  P.fc_b  = (const float*)d_in[38];
  P.out   = (float*)d_out;

  // ---- graph stages ----
  k_zero <<<dim3((TOTF+255)/256 + 1), 256, 0, stream>>>();
  k_pre  <<<dim3((NH*HID+CAT+255)/256), 256, 0, stream>>>(P);
  k_e2p  <<<dim3(E/TE2,NH,2),128, 0, stream>>>(P);   // e2 partials + ew1/ewv + EDOTH (fused)
  k_pairs<<<dim3((E+255)/256,2), 256, 0, stream>>>(P);
  k_h0   <<<dim3((2*N*HID+255)/256), 256, 0, stream>>>(P);
  k_gpool_gate<<<dim3(N,2), 256, 0, stream>>>(P, OH0, HID, -1, P.g1_w, P.g1_b);
  k_gpool_out <<<dim3(1,2), 256, 0, stream>>>(P, OH0, HID, -1, 0);
  k_Wh   <<<dim3(N,NH,2), 128, 0, stream>>>(P);
  k_asad <<<dim3(NH,2),   256, 0, stream>>>(P);
  k_att1 <<<dim3(N,NH,2), 128, 0, stream>>>(P);
  k_xw1  <<<dim3(N,2,2),  256, 0, stream>>>(P);
  k_s1   <<<dim3((E+255)/256,2), 256, 0, stream>>>(P);
  k_ns   <<<dim3(1,2),    256, 0, stream>>>(ODEG1, OSS1, ONS1);
  k_gpool_gate<<<dim3(N,2), 256, 0, stream>>>(P, OH1, CAT, ONS1, P.g2_w, P.g2_b);
  k_gpool_out <<<dim3(8,2), 256, 0, stream>>>(P, OH1, CAT, ONS1, HID);
  k_Wh2  <<<dim3(N,2),    512, 0, stream>>>(P);
  k_asad2<<<dim3(2),      256, 0, stream>>>(P);
  k_att2 <<<dim3(N,2),    128, 0, stream>>>(P);
  k_ew2fin<<<dim3(E/TE2,2),128, 0, stream>>>(P);
  k_xsd2 <<<dim3(2),      256, 0, stream>>>(P);
  k_s2   <<<dim3((E+255)/256,2), 256, 0, stream>>>(P);
  k_ns   <<<dim3(1,2),    256, 0, stream>>>(ODEG2, OSS2, ONS2);
  k_gpool_gate<<<dim3(N,2), 256, 0, stream>>>(P, OH2B, OUTD, ONS2, P.g3_w, P.g3_b);
  k_gpool_out <<<dim3(1,2), 256, 0, stream>>>(P, OH2B, OUTD, ONS2, HID+CAT);

  // ---- LSTM stack + classifier ----
  k_lstm_xg <<<dim3(512), 256, 0, stream>>>(P, 0);
  k_lstm_rec<<<dim3(2),   512, 0, stream>>>(P, 0);
  k_lstm_xg <<<dim3(512), 256, 0, stream>>>(P, 1);
  k_lstm_rec<<<dim3(2),   512, 0, stream>>>(P, 1);
  k_final<<<dim3(1), 256, 0, stream>>>(P);
}

// Round 13
// 470.603 us; speedup vs baseline: 3.8613x; 1.0554x over previous
//
#include <hip/hip_runtime.h>
#include <math.h>

#define DI static __device__ __forceinline__

DI float eluf(float x){ return x > 0.f ? x : expm1f(x); }
DI float lreluf(float x){ return x > 0.f ? x : 0.2f*x; }
DI float sigmf(float x){ return 1.f/(1.f+expf(-x)); }

constexpr int N=200, E=3200, HID=64, NH=16, OUTD=128, CAT=2048, SEQD=2240;

// ---- per-graph f32 scratch offsets (in floats) ----
constexpr int OH0   = 0;
constexpr int OWH   = OH0 + N*HID;
constexpr int OASN  = OWH + NH*N*OUTD;
constexpr int OADN  = OASN + NH*N;
constexpr int OH1   = OADN + NH*N;
constexpr int OXW1  = OH1 + N*CAT;
constexpr int OXW2  = OXW1 + 256;
constexpr int OEW1  = OXW2 + 256;
constexpr int OS1   = OEW1 + E;
constexpr int ODEG1 = OS1 + E;
constexpr int OSS1  = ODEG1 + 256;   // = ODEG1+256 (relied on for inline ns)
constexpr int ONS1  = OSS1 + 256;
constexpr int OWH2  = ONS1 + 256;
constexpr int OAS2  = OWH2 + N*OUTD;
constexpr int OAD2  = OAS2 + 256;
constexpr int OEWV  = OAD2 + 256;
constexpr int OH2B  = OEWV + E;
constexpr int OXS2  = OH2B + N*OUTD;
constexpr int OXD2  = OXS2 + 256;
constexpr int OEW2  = OXD2 + 256;
constexpr int OS2   = OEW2 + E;
constexpr int ODEG2 = OS2 + E;
constexpr int OSS2  = ODEG2 + 256;   // = ODEG2+256
constexpr int ONS2  = OSS2 + 256;
constexpr int OGATE = ONS2 + 256;
constexpr int PGF   = OGATE + 256;
constexpr int GLOBF = 10624;
constexpr int TOTF  = GLOBF + 2*PGF;

// ---- static device scratch: independent of ws_size ----
__device__ float G_F[TOTF];
__device__ float G_E2PART[(size_t)NH*2*E*OUTD];   // per-head e2 partials
__device__ float G_EDOTH[2*NH*E];                  // eattr@weae per (g,h,e)
__device__ float G_WHHT[2*2*128*512];              // transposed Whh [layer][dir][k][gate]
__device__ int   G_PIDX[2*N*N];

DI float* gf(int g){ return G_F + GLOBF + (size_t)g*PGF; }
DI float* gwe_ae(){ return G_F; }
DI float* gv_e(){ return G_F + 1024; }
DI float* gy0(){ return G_F + 3072; }
DI float* gy1(){ return G_F + 3584; }
DI float* gxseq(){ return G_F + 4096; }
DI float* gxg(){ return G_F + 8576; }
DI int*   gpidx(int g){ return G_PIDX + g*N*N; }

struct GraphIn {
  const float *feat, *eattr, *adj, *n2n;
  const int   *eidx;
};

struct Params {
  GraphIn g[2];
  const float *W_h, *W_gat, *a_src, *a_dst, *a_e, *We_gat;
  const float *W_out, *ao_src, *ao_dst, *ao_e, *We_out;
  const float *ep1_w, *ep1_b, *ep2_w, *ep2_b;
  const float *g1_w, *g1_b, *g2_w, *g2_b, *g3_w, *g3_b;
  const float *Wih0, *Whh0, *b0, *Wih1, *Whh1, *b1, *fc_w, *fc_b;
  float *out;
};

// ---------------- zero scratch; pairIdx=-1 ----------------
__global__ void k_zero(){
  int idx = blockIdx.x*256 + threadIdx.x;
  if (idx < TOTF) G_F[idx] = 0.f;
  if (idx < 2*N*N) G_PIDX[idx] = -1;
}

// ---- Whh transpose: [l][d][gate][k] -> [l][d][k][gate] ----
__global__ void k_whhT(Params P){
  int idx = blockIdx.x*256 + threadIdx.x;
  if (idx >= 2*2*512*128) return;
  int l = idx >> 17;
  int r = idx & 131071;
  int d = r >> 16;
  int r2 = r & 65535;
  int gate = r2 & 511;
  int k = r2 >> 9;
  const float* Whh = l ? P.Whh1 : P.Whh0;
  G_WHHT[idx] = Whh[((size_t)d*512+gate)*128 + k];
}

// ---- precontract We@a_e vectors: one wave per dot ----
__global__ void k_pre(Params P){
  int gid = blockIdx.x*4 + (threadIdx.x>>6);
  int lane = threadIdx.x & 63;
  if (gid < NH*HID){
    int h = gid/HID, c = gid%HID;
    const float* W = P.We_gat + (size_t)(h*HID+c)*OUTD;
    const float* a = P.a_e + h*OUTD;
    float acc = 0.f;
    for (int o=lane;o<OUTD;o+=64) acc += W[o]*a[o];
    for (int off=32;off>0;off>>=1) acc += __shfl_down(acc,off);
    if (lane==0) gwe_ae()[gid] = acc;
  } else if (gid < NH*HID+CAT){
    int c = gid - NH*HID;
    const float* W = P.We_out + (size_t)c*OUTD;
    float acc = 0.f;
    for (int o=lane;o<OUTD;o+=64) acc += W[o]*P.ao_e[o];
    for (int off=32;off>0;off>>=1) acc += __shfl_down(acc,off);
    if (lane==0) gv_e()[c] = acc;
  }
}

// ---------------- h0 = elu(feat @ W_h) ----------------
__global__ void k_h0(Params P){
  int idx = blockIdx.x*256 + threadIdx.x;
  if (idx >= 2*N*HID) return;
  int g = idx/(N*HID), r = idx%(N*HID), n = r/HID, c = r%HID;
  const float* feat = P.g[g].feat;
  float acc = 0.f;
  for (int k=0;k<HID;k++) acc += feat[n*HID+k]*P.W_h[k*HID+c];
  gf(g)[OH0 + n*HID + c] = eluf(acc);
}

// ---- Wh[h] = h0 @ W_gat[h]; fused asn/adn reduction ----
__global__ void k_Wh(Params P){
  int n = blockIdx.x, h = blockIdx.y, g = blockIdx.z, o = threadIdx.x;
  __shared__ float hs[HID];
  __shared__ float sred[128], dred[128];
  float* f = gf(g);
  if (o < HID) hs[o] = f[OH0 + n*HID + o];
  __syncthreads();
  const float* W = P.W_gat + (size_t)h*HID*OUTD + o;
  float acc = 0.f;
  for (int c=0;c<HID;c++) acc += hs[c]*W[(size_t)c*OUTD];
  f[OWH + ((size_t)h*N + n)*OUTD + o] = acc;
  sred[o] = acc*P.a_src[h*OUTD+o];
  dred[o] = acc*P.a_dst[h*OUTD+o];
  __syncthreads();
  for (int s=64;s>0;s>>=1){ if (o<s){ sred[o]+=sred[o+s]; dred[o]+=dred[o+s]; } __syncthreads(); }
  if (o==0){ f[OASN+h*N+n]=sred[0]; f[OADN+h*N+n]=dred[0]; }
}

// ---- GAT layer 1: 4 nodes per block; edge term via EDOTH lookup ----
__global__ void k_att1(Params P){
  int nb = blockIdx.x, h = blockIdx.y, g = blockIdx.z, tid = threadIdx.x;  // 128 thr
  int n0 = nb*4;
  __shared__ float z[4][N];
  __shared__ float red[128];
  __shared__ float sinv[4];
  float* f = gf(g);
  const float* adj = P.g[g].adj;
  const int* pidx = gpidx(g);
  const float* edoth = G_EDOTH + ((size_t)g*NH + h)*E;
  const float* adn = f + OADN + h*N;
  for (int i=0;i<4;i++){
    float asn = f[OASN + h*N + n0+i];
    for (int j = tid; j < N; j += 128){
      float a = adj[(n0+i)*N + j];
      float zz;
      if (a > 0.f){
        int p = pidx[(n0+i)*N + j];
        float ee = (p >= 0) ? edoth[p] : 0.f;
        zz = lreluf(asn + adn[j] + ee);
      } else zz = -1e9f;
      z[i][j] = zz;
    }
  }
  __syncthreads();
  for (int i=0;i<4;i++){
    float m = -3e38f;
    for (int j = tid; j < N; j += 128) m = fmaxf(m, z[i][j]);
    red[tid] = m; __syncthreads();
    for (int s=64;s>0;s>>=1){ if (tid<s) red[tid]=fmaxf(red[tid],red[tid+s]); __syncthreads(); }
    m = red[0]; __syncthreads();
    float ssum = 0.f;
    for (int j = tid; j < N; j += 128){ float e = expf(z[i][j]-m); z[i][j]=e; ssum += e; }
    red[tid] = ssum; __syncthreads();
    for (int s=64;s>0;s>>=1){ if (tid<s) red[tid]+=red[tid+s]; __syncthreads(); }
    if (tid==0) sinv[i] = 1.f/red[0];
    __syncthreads();
  }
  const float* wh = f + OWH + (size_t)h*N*OUTD;
  float a0=0.f,a1=0.f,a2=0.f,a3=0.f;
  for (int j=0;j<N;j++){
    float w = wh[(size_t)j*OUTD + tid];
    a0 += z[0][j]*w; a1 += z[1][j]*w; a2 += z[2][j]*w; a3 += z[3][j]*w;
  }
  f[OH1 + (size_t)(n0+0)*CAT + h*OUTD + tid] = eluf(a0*sinv[0]);
  f[OH1 + (size_t)(n0+1)*CAT + h*OUTD + tid] = eluf(a1*sinv[1]);
  f[OH1 + (size_t)(n0+2)*CAT + h*OUTD + tid] = eluf(a2*sinv[2]);
  f[OH1 + (size_t)(n0+3)*CAT + h*OUTD + tid] = eluf(a3*sinv[3]);
}

// ---- pool1 node dots: both weight rows in one pass ----
__global__ void k_xw1(Params P){
  int n = blockIdx.x, g = blockIdx.y, tid = threadIdx.x;
  __shared__ float s1b[256], s2b[256];
  float* f = gf(g);
  const float* x = f + OH1 + (size_t)n*CAT;
  float a1 = 0.f, a2 = 0.f;
  for (int c = tid; c < CAT; c += 256){
    float xv = x[c];
    a1 += xv*P.ep1_w[c];
    a2 += xv*P.ep1_w[CAT+c];
  }
  s1b[tid]=a1; s2b[tid]=a2; __syncthreads();
  for (int s=128;s>0;s>>=1){ if (tid<s){ s1b[tid]+=s1b[tid+s]; s2b[tid]+=s2b[tid+s]; } __syncthreads(); }
  if (tid==0){ f[OXW1+n]=s1b[0]; f[OXW2+n]=s2b[0]; }
}

// ---------------- pool1 edge scores + segment sums ----------------
__global__ void k_s1(Params P){
  int e = blockIdx.x*256 + threadIdx.x, g = blockIdx.y;
  if (e >= E) return;
  float* f = gf(g);
  const int* ei = P.g[g].eidx;
  int s = ei[e], d = ei[E+e];
  float v = sigmf(f[OXW1+s] + f[OXW2+d] + f[OEW1+e] + P.ep1_b[0]);
  f[OS1+e] = v;
  atomicAdd(&f[OSS1+s], v);
  atomicAdd(&f[ODEG1+s], 1.f);
}

// ---------------- pairIdx: last edge wins ----------------
__global__ void k_pairs(Params P){
  int e = blockIdx.x*256 + threadIdx.x, g = blockIdx.y;
  if (e >= E) return;
  const int* ei = P.g[g].eidx;
  atomicMax(&gpidx(g)[ei[e]*N + ei[E+e]], e);
}

// ---- global attention pool (gate); odeg>=0 -> inline node-scale ss/(deg+eps) ----
__global__ void k_gpool_gate(Params P, int xoff, int D, int odeg, const float* w, const float* b){
  int n = blockIdx.x, g = blockIdx.y, tid = threadIdx.x;
  __shared__ float sb[256];
  float* f = gf(g);
  const float* x = f + xoff + (size_t)n*D;
  float acc = 0.f;
  for (int c = tid; c < D; c += 256) acc += x[c]*w[c];
  sb[tid] = acc; __syncthreads();
  for (int s=128;s>0;s>>=1){ if (tid<s) sb[tid]+=sb[tid+s]; __syncthreads(); }
  if (tid==0){
    float sc = odeg>=0 ? f[odeg+256+n]/(f[odeg+n]+1e-6f) : 1.f;
    f[OGATE+n] = sigmf(sb[0]*sc + b[0]);
  }
}

// ---- gpool output: column-tiled across grid.x ----
__global__ void k_gpool_out(Params P, int xoff, int D, int odeg, int outoff){
  int cb = blockIdx.x, g = blockIdx.y, tid = threadIdx.x;
  __shared__ float att[N];
  __shared__ float sb[256];
  float* f = gf(g);
  float m = -3e38f;
  for (int n = tid; n < N; n += 256) m = fmaxf(m, f[OGATE+n]);
  sb[tid] = m; __syncthreads();
  for (int s=128;s>0;s>>=1){ if (tid<s) sb[tid]=fmaxf(sb[tid],sb[tid+s]); __syncthreads(); }
  m = sb[0]; __syncthreads();
  float ss = 0.f;
  for (int n = tid; n < N; n += 256){ float e = expf(f[OGATE+n]-m); att[n]=e; ss += e; }
  sb[tid] = ss; __syncthreads();
  for (int s=128;s>0;s>>=1){ if (tid<s) sb[tid]+=sb[tid+s]; __syncthreads(); }
  float inv = 1.f/sb[0]; __syncthreads();
  for (int n = tid; n < N; n += 256){
    float sc = odeg>=0 ? f[odeg+256+n]/(f[odeg+n]+1e-6f) : 1.f;
    att[n] *= inv*sc;
  }
  __syncthreads();
  int c = cb*256 + tid;
  if (c < D){
    const float* x = f + xoff;
    float acc = 0.f;
    for (int n=0;n<N;n++) acc += att[n]*x[(size_t)n*D + c];
    gxseq()[g*SEQD + outoff + c] = acc;
  }
}

// ---- Wh2 = (h1cat @ W_out) * ns1 ; 512 thr, in-block K-split; inline ns ----
__global__ void k_Wh2(Params P){
  int n = blockIdx.x, g = blockIdx.y, tid = threadIdx.x;   // 512 threads
  int kq = tid >> 7, o = tid & 127;
  __shared__ float hrow[4][128];
  __shared__ float part[4][128];
  float* f = gf(g);
  const float* x = f + OH1 + (size_t)n*CAT;
  float acc = 0.f;
  for (int cc=0; cc<4; cc++){
    int c0 = kq*512 + cc*128;
    __syncthreads();
    hrow[kq][o] = x[c0 + o];
    __syncthreads();
    const float* W = P.W_out + (size_t)c0*OUTD + o;
    for (int j=0;j<128;j++) acc += hrow[kq][j]*W[(size_t)j*OUTD];
  }
  part[kq][o] = acc;
  __syncthreads();
  if (kq==0){
    float ns = f[OSS1+n]/(f[ODEG1+n]+1e-6f);
    float a = part[0][o]+part[1][o]+part[2][o]+part[3][o];
    f[OWH2 + (size_t)n*OUTD + o] = a*ns;
  }
}

__global__ void k_asad2(Params P){
  int g = blockIdx.x;
  float* f = gf(g);
  for (int n = threadIdx.x; n < N; n += 256){
    const float* wh = f + OWH2 + (size_t)n*OUTD;
    float s=0.f, d=0.f;
    for (int o=0;o<OUTD;o++){
      float v = wh[o];
      s += v*P.ao_src[o];
      d += v*P.ao_dst[o];
    }
    f[OAS2+n]=s; f[OAD2+n]=d;
  }
}

// ---- GAT layer 2; fused pool2 node dots (xs2/xd2) ----
__global__ void k_att2(Params P){
  int n = blockIdx.x, g = blockIdx.y, tid = threadIdx.x;
  __shared__ float z[N];
  __shared__ float red[128];
  __shared__ float dred[128];
  float* f = gf(g);
  const float* adj = P.g[g].adj;
  const int* pidx = gpidx(g);
  float asn = f[OAS2+n];
  const float* adn = f + OAD2;
  for (int j = tid; j < N; j += 128){
    float a = adj[n*N + j];
    float zz;
    if (a > 0.f){
      int p = pidx[n*N + j];
      float ee = (p >= 0) ? f[OEWV+p]*f[OS1+p] : 0.f;
      zz = lreluf(asn + adn[j] + ee);
    } else zz = -1e9f;
    z[j] = zz;
  }
  __syncthreads();
  float m = -3e38f;
  for (int j = tid; j < N; j += 128) m = fmaxf(m, z[j]);
  red[tid] = m; __syncthreads();
  for (int s=64;s>0;s>>=1){ if (tid<s) red[tid]=fmaxf(red[tid],red[tid+s]); __syncthreads(); }
  m = red[0]; __syncthreads();
  float ssum = 0.f;
  for (int j = tid; j < N; j += 128){ float e = expf(z[j]-m); z[j]=e; ssum += e; }
  red[tid] = ssum; __syncthreads();
  for (int s=64;s>0;s>>=1){ if (tid<s) red[tid]+=red[tid+s]; __syncthreads(); }
  float inv = 1.f/red[0]; __syncthreads();
  const float* wh = f + OWH2;
  float acc = 0.f;
  for (int j=0;j<N;j++){
    float w = z[j];
    if (w != 0.f) acc += w * wh[(size_t)j*OUTD + tid];
  }
  float v = acc*inv;
  f[OH2B + (size_t)n*OUTD + tid] = v;
  red[tid]  = v*P.ep2_w[tid];
  dred[tid] = v*P.ep2_w[OUTD+tid];
  __syncthreads();
  for (int s=64;s>0;s>>=1){ if (tid<s){ red[tid]+=red[tid+s]; dred[tid]+=dred[tid+s]; } __syncthreads(); }
  if (tid==0){ f[OXS2+n]=red[0]; f[OXD2+n]=dred[0]; }
}

// ---- e2 partial: register-tiled 4x4, fused ew1/ewv + EDOTH ----
constexpr int TE2 = 16;
__global__ __launch_bounds__(128, 2) void k_e2p(Params P){
  int e0 = blockIdx.x*TE2, h = blockIdx.y, g = blockIdx.z, tid = threadIdx.x; // 128 thr
  int cg = tid & 31, eg = tid >> 5;
  int c4 = cg*4, e4 = eg*4;
  __shared__ float es_t[HID][TE2+1];
  __shared__ float tcol_t[OUTD][TE2];
  const float* __restrict__ ea = P.g[g].eattr + (size_t)e0*HID;
  for (int i = tid; i < TE2*HID; i += 128) es_t[i & 63][i >> 6] = ea[i];
  __syncthreads();
  const float* __restrict__ W1 = P.We_gat + (size_t)h*HID*OUTD;
  const float* __restrict__ weae = gwe_ae() + h*HID;
  float t[4][4];
  float ed[4] = {0.f,0.f,0.f,0.f};
  #pragma unroll
  for (int i=0;i<4;i++){ t[i][0]=0.f; t[i][1]=0.f; t[i][2]=0.f; t[i][3]=0.f; }
  for (int c=0;c<HID;c++){
    float ev0 = es_t[c][e4+0], ev1 = es_t[c][e4+1], ev2 = es_t[c][e4+2], ev3 = es_t[c][e4+3];
    float4 w  = *(const float4*)&W1[(size_t)c*OUTD + c4];
    t[0][0]+=ev0*w.x; t[0][1]+=ev0*w.y; t[0][2]+=ev0*w.z; t[0][3]+=ev0*w.w;
    t[1][0]+=ev1*w.x; t[1][1]+=ev1*w.y; t[1][2]+=ev1*w.z; t[1][3]+=ev1*w.w;
    t[2][0]+=ev2*w.x; t[2][1]+=ev2*w.y; t[2][2]+=ev2*w.z; t[2][3]+=ev2*w.w;
    t[3][0]+=ev3*w.x; t[3][1]+=ev3*w.y; t[3][2]+=ev3*w.z; t[3][3]+=ev3*w.w;
    float wc = weae[c];
    ed[0]+=ev0*wc; ed[1]+=ev1*wc; ed[2]+=ev2*wc; ed[3]+=ev3*wc;
  }
  if (cg==0){
    float* eo = G_EDOTH + ((size_t)g*NH+h)*E + e0 + e4;
    eo[0]=ed[0]; eo[1]=ed[1]; eo[2]=ed[2]; eo[3]=ed[3];
  }
  #pragma unroll
  for (int i=0;i<4;i++){
    t[i][0]=eluf(t[i][0]); t[i][1]=eluf(t[i][1]); t[i][2]=eluf(t[i][2]); t[i][3]=eluf(t[i][3]);
  }
  {
    float4 w1 = *(const float4*)&P.ep1_w[2*CAT + h*OUTD + c4];
    float4 wv = *(const float4*)&gv_e()[h*OUTD + c4];
    #pragma unroll
    for (int i=0;i<4;i++){
      float a1 = t[i][0]*w1.x + t[i][1]*w1.y + t[i][2]*w1.z + t[i][3]*w1.w;
      float a2 = t[i][0]*wv.x + t[i][1]*wv.y + t[i][2]*wv.z + t[i][3]*wv.w;
      for (int off=16;off>0;off>>=1){
        a1 += __shfl_down(a1,off,32);
        a2 += __shfl_down(a2,off,32);
      }
      if (cg==0){
        atomicAdd(&gf(g)[OEW1 + e0+e4+i], a1);
        atomicAdd(&gf(g)[OEWV + e0+e4+i], a2);
      }
    }
  }
  #pragma unroll
  for (int j=0;j<4;j++){
    int o = c4 + j;
    int slot = (eg + (o>>2)) & 3;
    float4 v; v.x=t[0][j]; v.y=t[1][j]; v.z=t[2][j]; v.w=t[3][j];
    *(float4*)&tcol_t[o][4*slot] = v;
  }
  __syncthreads();
  const float* __restrict__ W2 = P.We_out + (size_t)h*OUTD*OUTD;
  float acc[4][4];
  #pragma unroll
  for (int i=0;i<4;i++){ acc[i][0]=0.f; acc[i][1]=0.f; acc[i][2]=0.f; acc[i][3]=0.f; }
  #pragma unroll 4
  for (int o=0;o<OUTD;o++){
    int slot = (eg + (o>>2)) & 3;
    float4 tv = *(const float4*)&tcol_t[o][4*slot];
    float4 w  = *(const float4*)&W2[(size_t)o*OUTD + c4];
    acc[0][0]+=tv.x*w.x; acc[0][1]+=tv.x*w.y; acc[0][2]+=tv.x*w.z; acc[0][3]+=tv.x*w.w;
    acc[1][0]+=tv.y*w.x; acc[1][1]+=tv.y*w.y; acc[1][2]+=tv.y*w.z; acc[1][3]+=tv.y*w.w;
    acc[2][0]+=tv.z*w.x; acc[2][1]+=tv.z*w.y; acc[2][2]+=tv.z*w.z; acc[2][3]+=tv.z*w.w;
    acc[3][0]+=tv.w*w.x; acc[3][1]+=tv.w*w.y; acc[3][2]+=tv.w*w.z; acc[3][3]+=tv.w*w.w;
  }
  float* dst = G_E2PART + (((size_t)h*2 + g)*E + e0)*OUTD;
  #pragma unroll
  for (int i=0;i<4;i++){
    float4 v; v.x=acc[i][0]; v.y=acc[i][1]; v.z=acc[i][2]; v.w=acc[i][3];
    *(float4*)&dst[(size_t)(e4+i)*OUTD + c4] = v;
  }
}

// ---- finish: sum 16 head-partials, elu, dot ep2_w ----
__global__ void k_ew2fin(Params P){
  int e0 = blockIdx.x*TE2, g = blockIdx.y, tid = threadIdx.x;  // 128 thr
  __shared__ float lred[2][TE2];
  float* f = gf(g);
  float w2 = P.ep2_w[2*OUTD + tid];
  int lane = tid & 63, wvi = tid >> 6;
  for (int e=0;e<TE2;e++){
    const float* src = G_E2PART + ((size_t)g*E + e0 + e)*OUTD + tid;
    float a = 0.f;
    for (int h=0;h<NH;h++) a += src[(size_t)h*2*E*OUTD];
    float v = eluf(f[OS1+e0+e]*a) * w2;
    for (int off=32;off>0;off>>=1) v += __shfl_down(v,off);
    if (lane==0) lred[wvi][e]=v;
  }
  __syncthreads();
  if (tid < TE2) f[OEW2+e0+tid] = lred[0][tid]+lred[1][tid];
}

__global__ void k_s2(Params P){
  int e = blockIdx.x*256 + threadIdx.x, g = blockIdx.y;
  if (e >= E) return;
  float* f = gf(g);
  const int* ei = P.g[g].eidx;
  int s = ei[e], d = ei[E+e];
  float v = sigmf(f[OXS2+s] + f[OXD2+d] + f[OEW2+e] + P.ep2_b[0]);
  f[OS2+e] = v;
  atomicAdd(&f[OSS2+s], v);
  atomicAdd(&f[ODEG2+s], 1.f);
}

// ---- LSTM input projection ----
__global__ void k_lstm_xg(Params P, int layer){
  int gid = blockIdx.x*4 + (threadIdx.x>>6);
  int lane = threadIdx.x & 63;
  int t = gid >> 10;
  int rem = gid & 1023;
  int d = rem >> 9;
  int gate = rem & 511;
  const float* Wih = layer ? P.Wih1 : P.Wih0;
  const float* bb  = layer ? P.b1   : P.b0;
  const float* xin = layer ? gy0()  : gxseq();
  int Din = layer ? 256 : SEQD;
  const float* x = xin + t*Din;
  const float* Wr = Wih + ((size_t)d*512 + gate)*Din;
  float acc = 0.f;
  for (int k=lane; k<Din; k+=64) acc += x[k]*Wr[k];
  for (int off=32; off>0; off>>=1) acc += __shfl_down(acc, off);
  if (lane==0) gxg()[(t*2 + d)*512 + gate] = acc + bb[d*512 + gate];
}

// ---- LSTM recurrence: coalesced via transposed Whh ----
__global__ void k_lstm_rec(Params P, int layer){
  int d = blockIdx.x, tid = threadIdx.x;
  float* yout = layer ? gy1() : gy0();
  const float* T = G_WHHT + (size_t)(layer*2 + d)*128*512;
  __shared__ float h[128], c[128], gbuf[512];
  if (tid < 128){ h[tid]=0.f; c[tid]=0.f; }
  __syncthreads();
  for (int s=0;s<2;s++){
    int t = (d==0) ? s : 1-s;
    float acc = gxg()[(t*2 + d)*512 + tid];
    for (int k=0;k<128;k++) acc += h[k]*T[(size_t)k*512 + tid];
    gbuf[tid] = acc;
    __syncthreads();
    if (tid < 128){
      float ii = sigmf(gbuf[tid]);
      float ff = sigmf(gbuf[128+tid]);
      float gg = tanhf(gbuf[256+tid]);
      float oo = sigmf(gbuf[384+tid]);
      float cn = ff*c[tid] + ii*gg;
      c[tid] = cn;
      float hn = oo*tanhf(cn);
      h[tid] = hn;
      yout[t*256 + d*128 + tid] = hn;
    }
    __syncthreads();
  }
}

// ---------------- final FC + softmax ----------------
__global__ void k_final(Params P){
  int tid = threadIdx.x;
  __shared__ float sb[256], sb2[256];
  const float* x = gy1() + 256;
  sb[tid]  = x[tid]*P.fc_w[tid*2+0];
  sb2[tid] = x[tid]*P.fc_w[tid*2+1];
  __syncthreads();
  for (int s=128;s>0;s>>=1){ if (tid<s){ sb[tid]+=sb[tid+s]; sb2[tid]+=sb2[tid+s]; } __syncthreads(); }
  if (tid==0){
    float l0 = sb[0] + P.fc_b[0];
    float l1 = sb2[0] + P.fc_b[1];
    float m = fmaxf(l0,l1);
    float e0 = expf(l0-m), e1 = expf(l1-m), inv = 1.f/(e0+e1);
    P.out[0] = e0*inv;
    P.out[1] = e1*inv;
  }
}

extern "C" void kernel_launch(void* const* d_in, const int* in_sizes, int n_in,
                              void* d_out, int out_size, void* d_ws, size_t ws_size,
                              hipStream_t stream){
  Params P;
  for (int g=0; g<2; ++g){
    int b = g*5;
    P.g[g].feat  = (const float*)d_in[b+0];
    P.g[g].eidx  = (const int*)d_in[b+1];
    P.g[g].eattr = (const float*)d_in[b+2];
    P.g[g].adj   = (const float*)d_in[b+3];
    P.g[g].n2n   = (const float*)d_in[b+4];
  }
  P.W_h   = (const float*)d_in[10];
  P.W_gat = (const float*)d_in[11];
  P.a_src = (const float*)d_in[12];
  P.a_dst = (const float*)d_in[13];
  P.a_e   = (const float*)d_in[14];
  P.We_gat= (const float*)d_in[15];
  P.W_out = (const float*)d_in[16];
  P.ao_src= (const float*)d_in[17];
  P.ao_dst= (const float*)d_in[18];
  P.ao_e  = (const float*)d_in[19];
  P.We_out= (const float*)d_in[20];
  P.ep1_w = (const float*)d_in[21];
  P.ep1_b = (const float*)d_in[22];
  P.ep2_w = (const float*)d_in[23];
  P.ep2_b = (const float*)d_in[24];
  P.g1_w  = (const float*)d_in[25];
  P.g1_b  = (const float*)d_in[26];
  P.g2_w  = (const float*)d_in[27];
  P.g2_b  = (const float*)d_in[28];
  P.g3_w  = (const float*)d_in[29];
  P.g3_b  = (const float*)d_in[30];
  P.Wih0  = (const float*)d_in[31];
  P.Whh0  = (const float*)d_in[32];
  P.b0    = (const float*)d_in[33];
  P.Wih1  = (const float*)d_in[34];
  P.Whh1  = (const float*)d_in[35];
  P.b1    = (const float*)d_in[36];
  P.fc_w  = (const float*)d_in[37];
  P.fc_b  = (const float*)d_in[38];
  P.out   = (float*)d_out;

  // ---- graph stages ----
  k_zero <<<dim3((TOTF+255)/256 + 1), 256, 0, stream>>>();
  k_whhT <<<dim3((2*2*512*128+255)/256), 256, 0, stream>>>(P);
  k_pre  <<<dim3((NH*HID+CAT+3)/4), 256, 0, stream>>>(P);
  k_e2p  <<<dim3(E/TE2,NH,2),128, 0, stream>>>(P);   // e2 partials + ew1/ewv + EDOTH
  k_pairs<<<dim3((E+255)/256,2), 256, 0, stream>>>(P);
  k_h0   <<<dim3((2*N*HID+255)/256), 256, 0, stream>>>(P);
  k_gpool_gate<<<dim3(N,2), 256, 0, stream>>>(P, OH0, HID, -1, P.g1_w, P.g1_b);
  k_gpool_out <<<dim3(1,2), 256, 0, stream>>>(P, OH0, HID, -1, 0);
  k_Wh   <<<dim3(N,NH,2), 128, 0, stream>>>(P);       // + fused asn/adn
  k_att1 <<<dim3(N/4,NH,2), 128, 0, stream>>>(P);     // 4 nodes/block
  k_xw1  <<<dim3(N,2),    256, 0, stream>>>(P);       // both dots fused
  k_s1   <<<dim3((E+255)/256,2), 256, 0, stream>>>(P);
  k_gpool_gate<<<dim3(N,2), 256, 0, stream>>>(P, OH1, CAT, ODEG1, P.g2_w, P.g2_b);
  k_gpool_out <<<dim3(8,2), 256, 0, stream>>>(P, OH1, CAT, ODEG1, HID);
  k_Wh2  <<<dim3(N,2),    512, 0, stream>>>(P);
  k_asad2<<<dim3(2),      256, 0, stream>>>(P);
  k_att2 <<<dim3(N,2),    128, 0, stream>>>(P);       // + fused xs2/xd2
  k_ew2fin<<<dim3(E/TE2,2),128, 0, stream>>>(P);
  k_s2   <<<dim3((E+255)/256,2), 256, 0, stream>>>(P);
  k_gpool_gate<<<dim3(N,2), 256, 0, stream>>>(P, OH2B, OUTD, ODEG2, P.g3_w, P.g3_b);
  k_gpool_out <<<dim3(1,2), 256, 0, stream>>>(P, OH2B, OUTD, ODEG2, HID+CAT);

  // ---- LSTM stack + classifier ----
  k_lstm_xg <<<dim3(512), 256, 0, stream>>>(P, 0);
  k_lstm_rec<<<dim3(2),   512, 0, stream>>>(P, 0);
  k_lstm_xg <<<dim3(512), 256, 0, stream>>>(P, 1);
  k_lstm_rec<<<dim3(2),   512, 0, stream>>>(P, 1);
  k_final<<<dim3(1), 256, 0, stream>>>(P);
}